// Round 1
// baseline (860.749 us; speedup 1.0000x reference)
//
#include <hip/hip_runtime.h>
#include <hip/hip_bf16.h>

// GATv2 x3 + BN + ReLU + mean-pool + linear, fp32.
// N=100000 nodes, E=1.6M edges (+N self loops), F=128, H=64/32/16, G=64.

static constexpr int G_ = 64;

// ---------------- weight packing: Wcat[k][0:H]=Wl, [H:2H]=Wr ----------------
__global__ __launch_bounds__(256) void pack_w(
    const float* __restrict__ Wl, const float* __restrict__ Wr,
    const float* __restrict__ bl, const float* __restrict__ br,
    float* __restrict__ Wcat, float* __restrict__ bcat, int FI, int H) {
  int i = blockIdx.x * 256 + threadIdx.x;
  int FO = 2 * H;
  if (i < FI * FO) {
    int k = i / FO, c = i % FO;
    Wcat[i] = (c < H) ? Wl[k * H + c] : Wr[k * H + (c - H)];
  }
  if (i < FO) bcat[i] = (i < H) ? bl[i] : br[i - H];
}

// ---------------- transpose [N][FI] -> [FI][N] ----------------
template <int FI>
__global__ __launch_bounds__(256) void transpose_nf(
    const float* __restrict__ A, float* __restrict__ At, int N) {
  __shared__ float s[64][65];
  int n0 = blockIdx.x * 64, k0 = blockIdx.y * 64;
  int tid = threadIdx.x;
  for (int idx = tid; idx < 64 * 16; idx += 256) {
    int n = idx >> 4, c = idx & 15;
    float4 v = make_float4(0.f, 0.f, 0.f, 0.f);
    if (n0 + n < N)
      v = *reinterpret_cast<const float4*>(&A[(size_t)(n0 + n) * FI + k0 + c * 4]);
    s[n][c * 4 + 0] = v.x; s[n][c * 4 + 1] = v.y;
    s[n][c * 4 + 2] = v.z; s[n][c * 4 + 3] = v.w;
  }
  __syncthreads();
  for (int idx = tid; idx < 64 * 16; idx += 256) {
    int k = idx >> 4, c = idx & 15;
    int n = c * 4;
    if (n0 + n + 3 < N) {
      float4 v = make_float4(s[n][k], s[n + 1][k], s[n + 2][k], s[n + 3][k]);
      *reinterpret_cast<float4*>(&At[(size_t)(k0 + k) * N + n0 + n]) = v;
    } else {
      for (int j = 0; j < 4; j++)
        if (n0 + n + j < N) At[(size_t)(k0 + k) * N + n0 + n + j] = s[n + j][k];
    }
  }
}

// ---------------- CSR build ----------------
__global__ __launch_bounds__(256) void edge_hist(
    const int* __restrict__ ei, int* __restrict__ deg, int E, int Etot) {
  for (int i = blockIdx.x * 256 + threadIdx.x; i < Etot; i += gridDim.x * 256) {
    int dst = (i < E) ? ei[E + i] : (i - E);
    atomicAdd(&deg[dst], 1);
  }
}

__global__ __launch_bounds__(256) void scan1(
    const int* __restrict__ deg, int* __restrict__ part, int* __restrict__ bsums, int n) {
  __shared__ int ts[256];
  int t = threadIdx.x, b = blockIdx.x;
  int base = b * 1024 + t * 4;
  int d[4];
#pragma unroll
  for (int q = 0; q < 4; q++) d[q] = (base + q < n) ? deg[base + q] : 0;
  int s = d[0] + d[1] + d[2] + d[3];
  ts[t] = s;
  __syncthreads();
  for (int o = 1; o < 256; o <<= 1) {
    int v = (t >= o) ? ts[t - o] : 0;
    __syncthreads();
    ts[t] += v;
    __syncthreads();
  }
  int incl = ts[t];
  if (t == 255) bsums[b] = incl;
  int run = incl - s;
#pragma unroll
  for (int q = 0; q < 4; q++) {
    if (base + q < n) part[base + q] = run;
    run += d[q];
  }
}

__global__ void scan2(int* bsums, int nb) {
  if (threadIdx.x == 0 && blockIdx.x == 0) {
    int r = 0;
    for (int i = 0; i < nb; i++) { int t = bsums[i]; bsums[i] = r; r += t; }
  }
}

__global__ __launch_bounds__(256) void scan3(
    int* __restrict__ rp, int* __restrict__ cur, const int* __restrict__ bsums,
    int n, int Etot) {
  int i = blockIdx.x * 256 + threadIdx.x;
  if (i < n) {
    int v = rp[i] + bsums[i >> 10];
    rp[i] = v; cur[i] = v;
  }
  if (i == 0) rp[n] = Etot;
}

__global__ __launch_bounds__(256) void scatter_edges(
    const int* __restrict__ ei, int* __restrict__ cur, int* __restrict__ ssrc,
    int E, int Etot) {
  for (int i = blockIdx.x * 256 + threadIdx.x; i < Etot; i += gridDim.x * 256) {
    int src, dst;
    if (i < E) { src = ei[i]; dst = ei[E + i]; } else { src = i - E; dst = i - E; }
    int pos = atomicAdd(&cur[dst], 1);
    ssrc[pos] = src;
  }
}

// ---------------- GEMM: C[N][FO] = At^T[N][FI] @ Wcat[FI][FO] + bcat ----------------
template <int FI, int FO>
__global__ __launch_bounds__(256) void gemm_fmaj(
    const float* __restrict__ At, const float* __restrict__ Wcat,
    const float* __restrict__ bcat, float* __restrict__ C, int N) {
  constexpr int KC = 32;
  constexpr int HP = FO / 16;
  __shared__ float As[FI * 64];
  __shared__ float Ws[KC * FO];
  int tid = threadIdx.x;
  int ng = tid & 15, hg = tid >> 4;
  int n0 = blockIdx.x * 64;

  if (n0 + 64 <= N) {
    for (int idx = tid; idx < FI * 16; idx += 256) {
      int k = idx >> 4, c = idx & 15;
      *reinterpret_cast<float4*>(&As[k * 64 + c * 4]) =
          *reinterpret_cast<const float4*>(&At[(size_t)k * N + n0 + c * 4]);
    }
  } else {
    for (int idx = tid; idx < FI * 64; idx += 256) {
      int k = idx >> 6, nn = idx & 63;
      As[k * 64 + nn] = (n0 + nn < N) ? At[(size_t)k * N + n0 + nn] : 0.f;
    }
  }

  float acc[4][HP];
#pragma unroll
  for (int i = 0; i < 4; i++)
#pragma unroll
    for (int j = 0; j < HP; j++) acc[i][j] = 0.f;

  for (int kc = 0; kc < FI; kc += KC) {
    __syncthreads();
    for (int idx = tid; idx < KC * FO / 4; idx += 256)
      *reinterpret_cast<float4*>(&Ws[idx * 4]) =
          *reinterpret_cast<const float4*>(&Wcat[kc * FO + idx * 4]);
    __syncthreads();
#pragma unroll
    for (int kk = 0; kk < KC; kk++) {
      float a_[4];
#pragma unroll
      for (int i = 0; i < 4; i++) a_[i] = As[(kc + kk) * 64 + ng * 4 + i];
      float w_[HP];
#pragma unroll
      for (int j = 0; j < HP; j++) w_[j] = Ws[kk * FO + hg * HP + j];
#pragma unroll
      for (int i = 0; i < 4; i++)
#pragma unroll
        for (int j = 0; j < HP; j++) acc[i][j] += a_[i] * w_[j];
    }
  }

#pragma unroll
  for (int i = 0; i < 4; i++) {
    int n = n0 + ng * 4 + i;
    if (n < N) {
#pragma unroll
      for (int j = 0; j < HP; j++)
        C[(size_t)n * FO + hg * HP + j] = acc[i][j] + bcat[hg * HP + j];
    }
  }
}

// ---------------- GATv2 aggregation: online softmax, one wave per dst node ----------------
template <int H>
__global__ __launch_bounds__(256) void gat_agg(
    const float* __restrict__ xlr, const float* __restrict__ att,
    const float* __restrict__ bias, const int* __restrict__ rp,
    const int* __restrict__ ssrc, float* __restrict__ out, int N) {
  constexpr int S = 64 / H;
  constexpr int LOGH = (H == 64) ? 6 : (H == 32) ? 5 : 4;
  int gtid = blockIdx.x * 256 + threadIdx.x;
  int v = gtid >> 6;
  if (v >= N) return;
  int lane = threadIdx.x & 63;
  int h = lane & (H - 1);
  int s = lane >> LOGH;

  float xr = xlr[(size_t)v * (2 * H) + H + h];
  float a = att[h];
  int beg = rp[v], end = rp[v + 1];
  float m = -3.0e38f, d = 0.f, acc = 0.f;
  for (int j = beg + s; j < end; j += S) {
    int u = ssrc[j];
    float xlv = xlr[(size_t)u * (2 * H) + h];
    float t = xlv + xr;
    t = (t > 0.f) ? t : 0.2f * t;
    t *= a;
#pragma unroll
    for (int o = H / 2; o >= 1; o >>= 1) t += __shfl_xor(t, o);
    float mn = fmaxf(m, t);
    float sc = __expf(m - mn);
    float w = __expf(t - mn);
    d = d * sc + w;
    acc = acc * sc + w * xlv;
    m = mn;
  }
#pragma unroll
  for (int o = H; o < 64; o <<= 1) {
    float mo = __shfl_xor(m, o);
    float d2 = __shfl_xor(d, o);
    float a2 = __shfl_xor(acc, o);
    float mn = fmaxf(m, mo);
    float s1 = __expf(m - mn), s2 = __expf(mo - mn);
    d = d * s1 + d2 * s2;
    acc = acc * s1 + a2 * s2;
    m = mn;
  }
  out[(size_t)v * H + h] = acc / (d + 1e-16f) + bias[h];
}

// ---------------- BatchNorm ----------------
template <int H>
__global__ __launch_bounds__(256) void bn_stats(
    const float* __restrict__ X, float* __restrict__ stats, int N) {
  __shared__ float ls[256], ls2[256];
  int tid = threadIdx.x;
  int h = tid % H;
  constexpr int RPB = 256 / H;
  int r0 = blockIdx.x * RPB + tid / H;
  float s = 0.f, s2 = 0.f;
  for (int n = r0; n < N; n += gridDim.x * RPB) {
    float val = X[(size_t)n * H + h];
    s += val; s2 += val * val;
  }
  ls[tid] = s; ls2[tid] = s2;
  __syncthreads();
  if (tid < H) {
    for (int g = 1; g < RPB; g++) { s += ls[tid + g * H]; s2 += ls2[tid + g * H]; }
    atomicAdd(&stats[h], s);
    atomicAdd(&stats[H + h], s2);
  }
}

__global__ void bn_finalize(
    const float* __restrict__ stats, const float* __restrict__ gamma,
    const float* __restrict__ beta, float* __restrict__ ss, int H, int N) {
  int h = threadIdx.x;
  if (h < H) {
    float mean = stats[h] / (float)N;
    float var = stats[H + h] / (float)N - mean * mean;
    float istd = rsqrtf(var + 1e-5f);
    float sc = gamma[h] * istd;
    ss[h] = sc;
    ss[H + h] = beta[h] - mean * sc;
  }
}

// BN + ReLU, write transposed [H][N] (layers 1,2 feed the next GEMM)
template <int H>
__global__ __launch_bounds__(256) void bn_apply_T(
    const float* __restrict__ X, const float* __restrict__ ss,
    float* __restrict__ Yt, int N) {
  __shared__ float s[64][65];
  int n0 = blockIdx.x * 64;
  int tid = threadIdx.x;
  for (int idx = tid; idx < 64 * (H / 4); idx += 256) {
    int n = idx / (H / 4), c = idx % (H / 4);
    float4 v = make_float4(0.f, 0.f, 0.f, 0.f);
    if (n0 + n < N)
      v = *reinterpret_cast<const float4*>(&X[(size_t)(n0 + n) * H + c * 4]);
    s[n][c * 4 + 0] = v.x; s[n][c * 4 + 1] = v.y;
    s[n][c * 4 + 2] = v.z; s[n][c * 4 + 3] = v.w;
  }
  __syncthreads();
  for (int idx = tid; idx < H * 16; idx += 256) {
    int k = idx >> 4, c = idx & 15;
    int n = c * 4;
    float sc = ss[k], sh = ss[H + k];
    float t0 = s[n + 0][k] * sc + sh;
    float t1 = s[n + 1][k] * sc + sh;
    float t2 = s[n + 2][k] * sc + sh;
    float t3 = s[n + 3][k] * sc + sh;
    float4 v = make_float4(t0 > 0.f ? t0 : 0.f, t1 > 0.f ? t1 : 0.f,
                           t2 > 0.f ? t2 : 0.f, t3 > 0.f ? t3 : 0.f);
    if (n0 + n + 3 < N) {
      *reinterpret_cast<float4*>(&Yt[(size_t)k * N + n0 + n]) = v;
    } else {
      float tv[4] = {v.x, v.y, v.z, v.w};
      for (int j = 0; j < 4; j++)
        if (n0 + n + j < N) Yt[(size_t)k * N + n0 + n + j] = tv[j];
    }
  }
}

// BN + ReLU flat (layer 3, node-major for pooling), H = 16
__global__ __launch_bounds__(256) void bn_apply_flat(
    const float* __restrict__ X, const float* __restrict__ ss,
    float* __restrict__ Y, int total) {
  int i = blockIdx.x * 256 + threadIdx.x;
  if (i < total) {
    int h = i & 15;
    float t = X[i] * ss[h] + ss[16 + h];
    Y[i] = t > 0.f ? t : 0.f;
  }
}

// ---------------- mean-pool + final linear ----------------
__global__ __launch_bounds__(256) void pool_kernel(
    const float* __restrict__ X, const int* __restrict__ batch,
    float* __restrict__ pool, float* __restrict__ cnt, int N) {
  __shared__ float lp[G_ * 16];
  __shared__ float lc[G_];
  int tid = threadIdx.x;
  for (int j = tid; j < G_ * 16; j += 256) lp[j] = 0.f;
  if (tid < G_) lc[tid] = 0.f;
  __syncthreads();
  int tot = N * 16;
  for (int i = blockIdx.x * 256 + tid; i < tot; i += gridDim.x * 256) {
    int n = i >> 4, h = i & 15;
    int g = batch[n];
    atomicAdd(&lp[g * 16 + h], X[i]);
    if (h == 0) atomicAdd(&lc[g], 1.0f);
  }
  __syncthreads();
  for (int j = tid; j < G_ * 16; j += 256) atomicAdd(&pool[j], lp[j]);
  if (tid < G_) atomicAdd(&cnt[tid], lc[tid]);
}

__global__ void final_linear(
    const float* __restrict__ pool, const float* __restrict__ cnt,
    const float* __restrict__ linW, const float* __restrict__ linb,
    float* __restrict__ out) {
  int g = threadIdx.x;
  if (g < G_) {
    float c = fmaxf(cnt[g], 1.0f);
    float acc = 0.f;
    for (int h = 0; h < 16; h++) acc += (pool[g * 16 + h] / c) * linW[h];
    out[g] = acc + linb[0];
  }
}

// ---------------- launch ----------------
extern "C" void kernel_launch(void* const* d_in, const int* in_sizes, int n_in,
                              void* d_out, int out_size, void* d_ws, size_t ws_size,
                              hipStream_t stream) {
  const float* x = (const float*)d_in[0];
  const int* ei = (const int*)d_in[1];
  const int* batch = (const int*)d_in[2];
  const int N = in_sizes[0] / 128;
  const int E = in_sizes[1] / 2;
  const int Etot = E + N;

  char* wsb = (char*)d_ws;
  size_t off = 0;
  auto alloc = [&](size_t bytes) -> void* {
    void* p = wsb + off;
    off += (bytes + 255) & ~(size_t)255;
    return p;
  };
  float* R0 = (float*)alloc((size_t)128 * N * 4);   // x_t / h_t / L3 BN out
  float* R1 = (float*)alloc((size_t)128 * N * 4);   // xlr
  float* R2 = (float*)alloc((size_t)64 * N * 4);    // agg out
  int* deg = (int*)alloc((size_t)N * 4);
  int* row_ptr = (int*)alloc((size_t)(N + 1) * 4);
  int* cursor = (int*)alloc((size_t)N * 4);
  int* bsums = (int*)alloc(4096);
  int* ssrc = (int*)alloc((size_t)Etot * 4);
  float* Wc1 = (float*)alloc(16384 * 4);  float* bc1 = (float*)alloc(128 * 4);
  float* Wc2 = (float*)alloc(4096 * 4);   float* bc2 = (float*)alloc(64 * 4);
  float* Wc3 = (float*)alloc(1024 * 4);   float* bc3 = (float*)alloc(32 * 4);
  float* stats = (float*)alloc(128 * 4);
  float* ss = (float*)alloc(128 * 4);
  float* pool = (float*)alloc((G_ * 16 + G_) * 4);
  float* cnt = pool + G_ * 16;

  const float* Wl1 = (const float*)d_in[3];  const float* bl1 = (const float*)d_in[4];
  const float* Wr1 = (const float*)d_in[5];  const float* br1 = (const float*)d_in[6];
  const float* att1 = (const float*)d_in[7]; const float* bias1 = (const float*)d_in[8];
  const float* g1 = (const float*)d_in[9];   const float* b1 = (const float*)d_in[10];
  const float* Wl2 = (const float*)d_in[11]; const float* bl2 = (const float*)d_in[12];
  const float* Wr2 = (const float*)d_in[13]; const float* br2 = (const float*)d_in[14];
  const float* att2 = (const float*)d_in[15]; const float* bias2 = (const float*)d_in[16];
  const float* g2 = (const float*)d_in[17];  const float* b2 = (const float*)d_in[18];
  const float* Wl3 = (const float*)d_in[19]; const float* bl3 = (const float*)d_in[20];
  const float* Wr3 = (const float*)d_in[21]; const float* br3 = (const float*)d_in[22];
  const float* att3 = (const float*)d_in[23]; const float* bias3 = (const float*)d_in[24];
  const float* g3 = (const float*)d_in[25];  const float* b3 = (const float*)d_in[26];
  const float* linW = (const float*)d_in[27]; const float* linb = (const float*)d_in[28];
  float* out = (float*)d_out;

  int ntiles = (N + 63) / 64;
  int nb = (N + 1023) / 1024;

  // pack weights
  pack_w<<<64, 256, 0, stream>>>(Wl1, Wr1, bl1, br1, Wc1, bc1, 128, 64);
  pack_w<<<16, 256, 0, stream>>>(Wl2, Wr2, bl2, br2, Wc2, bc2, 64, 32);
  pack_w<<<4, 256, 0, stream>>>(Wl3, Wr3, bl3, br3, Wc3, bc3, 32, 16);

  // transpose x -> R0 [128][N]
  transpose_nf<128><<<dim3(ntiles, 2), 256, 0, stream>>>(x, R0, N);

  // CSR build
  hipMemsetAsync(deg, 0, (size_t)N * 4, stream);
  edge_hist<<<4096, 256, 0, stream>>>(ei, deg, E, Etot);
  scan1<<<nb, 256, 0, stream>>>(deg, row_ptr, bsums, N);
  scan2<<<1, 64, 0, stream>>>(bsums, nb);
  scan3<<<(N + 255) / 256, 256, 0, stream>>>(row_ptr, cursor, bsums, N, Etot);
  scatter_edges<<<4096, 256, 0, stream>>>(ei, cursor, ssrc, E, Etot);

  // ---- layer 1 ----
  gemm_fmaj<128, 128><<<ntiles, 256, 0, stream>>>(R0, Wc1, bc1, R1, N);
  gat_agg<64><<<(N * 64 + 255) / 256, 256, 0, stream>>>(R1, att1, bias1, row_ptr, ssrc, R2, N);
  hipMemsetAsync(stats, 0, 128 * 4, stream);
  bn_stats<64><<<512, 256, 0, stream>>>(R2, stats, N);
  bn_finalize<<<1, 64, 0, stream>>>(stats, g1, b1, ss, 64, N);
  bn_apply_T<64><<<ntiles, 256, 0, stream>>>(R2, ss, R0, N);

  // ---- layer 2 ----
  gemm_fmaj<64, 64><<<ntiles, 256, 0, stream>>>(R0, Wc2, bc2, R1, N);
  gat_agg<32><<<(N * 64 + 255) / 256, 256, 0, stream>>>(R1, att2, bias2, row_ptr, ssrc, R2, N);
  hipMemsetAsync(stats, 0, 128 * 4, stream);
  bn_stats<32><<<512, 256, 0, stream>>>(R2, stats, N);
  bn_finalize<<<1, 64, 0, stream>>>(stats, g2, b2, ss, 32, N);
  bn_apply_T<32><<<ntiles, 256, 0, stream>>>(R2, ss, R0, N);

  // ---- layer 3 ----
  gemm_fmaj<32, 32><<<ntiles, 256, 0, stream>>>(R0, Wc3, bc3, R1, N);
  gat_agg<16><<<(N * 64 + 255) / 256, 256, 0, stream>>>(R1, att3, bias3, row_ptr, ssrc, R2, N);
  hipMemsetAsync(stats, 0, 128 * 4, stream);
  bn_stats<16><<<512, 256, 0, stream>>>(R2, stats, N);
  bn_finalize<<<1, 64, 0, stream>>>(stats, g3, b3, ss, 16, N);
  bn_apply_flat<<<(N * 16 + 255) / 256, 256, 0, stream>>>(R2, ss, R0, N * 16);

  // ---- pool + linear ----
  hipMemsetAsync(pool, 0, (G_ * 16 + G_) * 4, stream);
  pool_kernel<<<2048, 256, 0, stream>>>(R0, batch, pool, cnt, N);
  final_linear<<<1, 64, 0, stream>>>(pool, cnt, linW, linb, out);
}

// Round 2
// 667.595 us; speedup vs baseline: 1.2893x; 1.2893x over previous
//
#include <hip/hip_runtime.h>
#include <hip/hip_bf16.h>

// GATv2 x3 + BN + ReLU + mean-pool + linear, fp32.
// N=100000 nodes, E=1.6M edges (+N self loops), F=128, H=64/32/16, G=64.

static constexpr int G_ = 64;

// ---------------- weight packing: Wcat[k][0:H]=Wl, [H:2H]=Wr ----------------
__global__ __launch_bounds__(256) void pack_w(
    const float* __restrict__ Wl, const float* __restrict__ Wr,
    const float* __restrict__ bl, const float* __restrict__ br,
    float* __restrict__ Wcat, float* __restrict__ bcat, int FI, int H) {
  int i = blockIdx.x * 256 + threadIdx.x;
  int FO = 2 * H;
  if (i < FI * FO) {
    int k = i / FO, c = i % FO;
    Wcat[i] = (c < H) ? Wl[k * H + c] : Wr[k * H + (c - H)];
  }
  if (i < FO) bcat[i] = (i < H) ? bl[i] : br[i - H];
}

// ---------------- transpose [N][FI] -> [FI][N] ----------------
template <int FI>
__global__ __launch_bounds__(256) void transpose_nf(
    const float* __restrict__ A, float* __restrict__ At, int N) {
  __shared__ float s[64][65];
  int n0 = blockIdx.x * 64, k0 = blockIdx.y * 64;
  int tid = threadIdx.x;
  for (int idx = tid; idx < 64 * 16; idx += 256) {
    int n = idx >> 4, c = idx & 15;
    float4 v = make_float4(0.f, 0.f, 0.f, 0.f);
    if (n0 + n < N)
      v = *reinterpret_cast<const float4*>(&A[(size_t)(n0 + n) * FI + k0 + c * 4]);
    s[n][c * 4 + 0] = v.x; s[n][c * 4 + 1] = v.y;
    s[n][c * 4 + 2] = v.z; s[n][c * 4 + 3] = v.w;
  }
  __syncthreads();
  for (int idx = tid; idx < 64 * 16; idx += 256) {
    int k = idx >> 4, c = idx & 15;
    int n = c * 4;
    if (n0 + n + 3 < N) {
      float4 v = make_float4(s[n][k], s[n + 1][k], s[n + 2][k], s[n + 3][k]);
      *reinterpret_cast<float4*>(&At[(size_t)(k0 + k) * N + n0 + n]) = v;
    } else {
      for (int j = 0; j < 4; j++)
        if (n0 + n + j < N) At[(size_t)(k0 + k) * N + n0 + n + j] = s[n + j][k];
    }
  }
}

// ---------------- CSR build ----------------
__global__ __launch_bounds__(256) void edge_hist(
    const int* __restrict__ ei, int* __restrict__ deg, int E, int Etot) {
  for (int i = blockIdx.x * 256 + threadIdx.x; i < Etot; i += gridDim.x * 256) {
    int dst = (i < E) ? ei[E + i] : (i - E);
    atomicAdd(&deg[dst], 1);
  }
}

__global__ __launch_bounds__(256) void scan1(
    const int* __restrict__ deg, int* __restrict__ part, int* __restrict__ bsums, int n) {
  __shared__ int ts[256];
  int t = threadIdx.x, b = blockIdx.x;
  int base = b * 1024 + t * 4;
  int d[4];
#pragma unroll
  for (int q = 0; q < 4; q++) d[q] = (base + q < n) ? deg[base + q] : 0;
  int s = d[0] + d[1] + d[2] + d[3];
  ts[t] = s;
  __syncthreads();
  for (int o = 1; o < 256; o <<= 1) {
    int v = (t >= o) ? ts[t - o] : 0;
    __syncthreads();
    ts[t] += v;
    __syncthreads();
  }
  int incl = ts[t];
  if (t == 255) bsums[b] = incl;
  int run = incl - s;
#pragma unroll
  for (int q = 0; q < 4; q++) {
    if (base + q < n) part[base + q] = run;
    run += d[q];
  }
}

__global__ void scan2(int* bsums, int nb) {
  if (threadIdx.x == 0 && blockIdx.x == 0) {
    int r = 0;
    for (int i = 0; i < nb; i++) { int t = bsums[i]; bsums[i] = r; r += t; }
  }
}

__global__ __launch_bounds__(256) void scan3(
    int* __restrict__ rp, int* __restrict__ cur, const int* __restrict__ bsums,
    int n, int Etot) {
  int i = blockIdx.x * 256 + threadIdx.x;
  if (i < n) {
    int v = rp[i] + bsums[i >> 10];
    rp[i] = v; cur[i] = v;
  }
  if (i == 0) rp[n] = Etot;
}

__global__ __launch_bounds__(256) void scatter_edges(
    const int* __restrict__ ei, int* __restrict__ cur, int* __restrict__ ssrc,
    int E, int Etot) {
  for (int i = blockIdx.x * 256 + threadIdx.x; i < Etot; i += gridDim.x * 256) {
    int src, dst;
    if (i < E) { src = ei[i]; dst = ei[E + i]; } else { src = i - E; dst = i - E; }
    int pos = atomicAdd(&cur[dst], 1);
    ssrc[pos] = src;
  }
}

// ---------------- GEMM: C[N][FO] = At^T[N][FI] @ Wcat[FI][FO] + bcat ----------------
template <int FI, int FO>
__global__ __launch_bounds__(256) void gemm_fmaj(
    const float* __restrict__ At, const float* __restrict__ Wcat,
    const float* __restrict__ bcat, float* __restrict__ C, int N) {
  constexpr int KC = 32;
  constexpr int HP = FO / 16;
  __shared__ float As[FI * 64];
  __shared__ float Ws[KC * FO];
  int tid = threadIdx.x;
  int ng = tid & 15, hg = tid >> 4;
  int n0 = blockIdx.x * 64;

  if (n0 + 64 <= N) {
    for (int idx = tid; idx < FI * 16; idx += 256) {
      int k = idx >> 4, c = idx & 15;
      *reinterpret_cast<float4*>(&As[k * 64 + c * 4]) =
          *reinterpret_cast<const float4*>(&At[(size_t)k * N + n0 + c * 4]);
    }
  } else {
    for (int idx = tid; idx < FI * 64; idx += 256) {
      int k = idx >> 6, nn = idx & 63;
      As[k * 64 + nn] = (n0 + nn < N) ? At[(size_t)k * N + n0 + nn] : 0.f;
    }
  }

  float acc[4][HP];
#pragma unroll
  for (int i = 0; i < 4; i++)
#pragma unroll
    for (int j = 0; j < HP; j++) acc[i][j] = 0.f;

  for (int kc = 0; kc < FI; kc += KC) {
    __syncthreads();
    for (int idx = tid; idx < KC * FO / 4; idx += 256)
      *reinterpret_cast<float4*>(&Ws[idx * 4]) =
          *reinterpret_cast<const float4*>(&Wcat[kc * FO + idx * 4]);
    __syncthreads();
#pragma unroll
    for (int kk = 0; kk < KC; kk++) {
      float a_[4];
#pragma unroll
      for (int i = 0; i < 4; i++) a_[i] = As[(kc + kk) * 64 + ng * 4 + i];
      float w_[HP];
#pragma unroll
      for (int j = 0; j < HP; j++) w_[j] = Ws[kk * FO + hg * HP + j];
#pragma unroll
      for (int i = 0; i < 4; i++)
#pragma unroll
        for (int j = 0; j < HP; j++) acc[i][j] += a_[i] * w_[j];
    }
  }

#pragma unroll
  for (int i = 0; i < 4; i++) {
    int n = n0 + ng * 4 + i;
    if (n < N) {
#pragma unroll
      for (int j = 0; j < HP; j++)
        C[(size_t)n * FO + hg * HP + j] = acc[i][j] + bcat[hg * HP + j];
    }
  }
}

// ---------------- GATv2 aggregation v2 ----------------
// One wave per dst node. Lane holds float4 of features: L = H/4 lanes per
// edge, C = 64/L edges concurrently, optional 2nd chain (UN2) per lane.
__device__ __forceinline__ float lrelu02(float z) {
  return (z > 0.f) ? z : 0.2f * z;
}

template <int H, bool UN2>
__global__ __launch_bounds__(256) void gat_agg2(
    const float* __restrict__ xlr, const float* __restrict__ att,
    const float* __restrict__ bias, const int* __restrict__ rp,
    const int* __restrict__ ssrc, float* __restrict__ out, int N) {
  constexpr int L = H / 4;    // lanes per edge
  constexpr int C = 64 / L;   // concurrent edges per wave
  int v = blockIdx.x * 4 + (threadIdx.x >> 6);
  if (v >= N) return;
  int lane = threadIdx.x & 63;
  int fl = lane % L;          // feature group: features fl*4 .. fl*4+3
  int sub = lane / L;         // edge slot

  const float4 xr4 = *reinterpret_cast<const float4*>(&xlr[(size_t)v * (2 * H) + H + fl * 4]);
  const float4 a4 = *reinterpret_cast<const float4*>(&att[fl * 4]);
  int beg = rp[v], end = rp[v + 1];

  float mA = -3.0e38f, dA = 0.f;
  float4 accA = make_float4(0.f, 0.f, 0.f, 0.f);
  float mB = -3.0e38f, dB = 0.f;
  float4 accB = make_float4(0.f, 0.f, 0.f, 0.f);

  constexpr int STEP = UN2 ? 2 * C : C;

  for (int j = beg + sub; j < end; j += STEP) {
    {
      int u = ssrc[j];
      float4 xl4 = *reinterpret_cast<const float4*>(&xlr[(size_t)u * (2 * H) + fl * 4]);
      float t = a4.x * lrelu02(xl4.x + xr4.x);
      t = fmaf(a4.y, lrelu02(xl4.y + xr4.y), t);
      t = fmaf(a4.z, lrelu02(xl4.z + xr4.z), t);
      t = fmaf(a4.w, lrelu02(xl4.w + xr4.w), t);
#pragma unroll
      for (int o = L / 2; o >= 1; o >>= 1) t += __shfl_xor(t, o);
      float mn = fmaxf(mA, t);
      float sc = __expf(mA - mn);
      float w = __expf(t - mn);
      dA = dA * sc + w;
      accA.x = fmaf(w, xl4.x, accA.x * sc);
      accA.y = fmaf(w, xl4.y, accA.y * sc);
      accA.z = fmaf(w, xl4.z, accA.z * sc);
      accA.w = fmaf(w, xl4.w, accA.w * sc);
      mA = mn;
    }
    if (UN2) {
      int j2 = j + C;
      if (j2 < end) {
        int u = ssrc[j2];
        float4 xl4 = *reinterpret_cast<const float4*>(&xlr[(size_t)u * (2 * H) + fl * 4]);
        float t = a4.x * lrelu02(xl4.x + xr4.x);
        t = fmaf(a4.y, lrelu02(xl4.y + xr4.y), t);
        t = fmaf(a4.z, lrelu02(xl4.z + xr4.z), t);
        t = fmaf(a4.w, lrelu02(xl4.w + xr4.w), t);
#pragma unroll
        for (int o = L / 2; o >= 1; o >>= 1) t += __shfl_xor(t, o);
        float mn = fmaxf(mB, t);
        float sc = __expf(mB - mn);
        float w = __expf(t - mn);
        dB = dB * sc + w;
        accB.x = fmaf(w, xl4.x, accB.x * sc);
        accB.y = fmaf(w, xl4.y, accB.y * sc);
        accB.z = fmaf(w, xl4.z, accB.z * sc);
        accB.w = fmaf(w, xl4.w, accB.w * sc);
        mB = mn;
      }
    }
  }

  // merge chain B into chain A (local, no shfl)
  if (UN2) {
    float mn = fmaxf(mA, mB);
    float s1 = __expf(mA - mn), s2 = __expf(mB - mn);
    dA = dA * s1 + dB * s2;
    accA.x = accA.x * s1 + accB.x * s2;
    accA.y = accA.y * s1 + accB.y * s2;
    accA.z = accA.z * s1 + accB.z * s2;
    accA.w = accA.w * s1 + accB.w * s2;
    mA = mn;
  }

  // butterfly merge across the C edge slots
#pragma unroll
  for (int o = L; o < 64; o <<= 1) {
    float mo = __shfl_xor(mA, o);
    float d2 = __shfl_xor(dA, o);
    float ax = __shfl_xor(accA.x, o);
    float ay = __shfl_xor(accA.y, o);
    float az = __shfl_xor(accA.z, o);
    float aw = __shfl_xor(accA.w, o);
    float mn = fmaxf(mA, mo);
    float s1 = __expf(mA - mn), s2 = __expf(mo - mn);
    dA = dA * s1 + d2 * s2;
    accA.x = accA.x * s1 + ax * s2;
    accA.y = accA.y * s1 + ay * s2;
    accA.z = accA.z * s1 + az * s2;
    accA.w = accA.w * s1 + aw * s2;
    mA = mn;
  }

  if (lane < L) {
    float inv = 1.f / (dA + 1e-16f);
    const float4 b4 = *reinterpret_cast<const float4*>(&bias[fl * 4]);
    float4 o4 = make_float4(fmaf(accA.x, inv, b4.x), fmaf(accA.y, inv, b4.y),
                            fmaf(accA.z, inv, b4.z), fmaf(accA.w, inv, b4.w));
    *reinterpret_cast<float4*>(&out[(size_t)v * H + fl * 4]) = o4;
  }
}

// ---------------- BatchNorm ----------------
template <int H>
__global__ __launch_bounds__(256) void bn_stats(
    const float* __restrict__ X, float* __restrict__ stats, int N) {
  __shared__ float ls[256], ls2[256];
  int tid = threadIdx.x;
  int h = tid % H;
  constexpr int RPB = 256 / H;
  int r0 = blockIdx.x * RPB + tid / H;
  float s = 0.f, s2 = 0.f;
  for (int n = r0; n < N; n += gridDim.x * RPB) {
    float val = X[(size_t)n * H + h];
    s += val; s2 += val * val;
  }
  ls[tid] = s; ls2[tid] = s2;
  __syncthreads();
  if (tid < H) {
    for (int g = 1; g < RPB; g++) { s += ls[tid + g * H]; s2 += ls2[tid + g * H]; }
    atomicAdd(&stats[h], s);
    atomicAdd(&stats[H + h], s2);
  }
}

__global__ void bn_finalize(
    const float* __restrict__ stats, const float* __restrict__ gamma,
    const float* __restrict__ beta, float* __restrict__ ss, int H, int N) {
  int h = threadIdx.x;
  if (h < H) {
    float mean = stats[h] / (float)N;
    float var = stats[H + h] / (float)N - mean * mean;
    float istd = rsqrtf(var + 1e-5f);
    float sc = gamma[h] * istd;
    ss[h] = sc;
    ss[H + h] = beta[h] - mean * sc;
  }
}

// BN + ReLU, write transposed [H][N] (layers 1,2 feed the next GEMM)
template <int H>
__global__ __launch_bounds__(256) void bn_apply_T(
    const float* __restrict__ X, const float* __restrict__ ss,
    float* __restrict__ Yt, int N) {
  __shared__ float s[64][65];
  int n0 = blockIdx.x * 64;
  int tid = threadIdx.x;
  for (int idx = tid; idx < 64 * (H / 4); idx += 256) {
    int n = idx / (H / 4), c = idx % (H / 4);
    float4 v = make_float4(0.f, 0.f, 0.f, 0.f);
    if (n0 + n < N)
      v = *reinterpret_cast<const float4*>(&X[(size_t)(n0 + n) * H + c * 4]);
    s[n][c * 4 + 0] = v.x; s[n][c * 4 + 1] = v.y;
    s[n][c * 4 + 2] = v.z; s[n][c * 4 + 3] = v.w;
  }
  __syncthreads();
  for (int idx = tid; idx < H * 16; idx += 256) {
    int k = idx >> 4, c = idx & 15;
    int n = c * 4;
    float sc = ss[k], sh = ss[H + k];
    float t0 = s[n + 0][k] * sc + sh;
    float t1 = s[n + 1][k] * sc + sh;
    float t2 = s[n + 2][k] * sc + sh;
    float t3 = s[n + 3][k] * sc + sh;
    float4 v = make_float4(t0 > 0.f ? t0 : 0.f, t1 > 0.f ? t1 : 0.f,
                           t2 > 0.f ? t2 : 0.f, t3 > 0.f ? t3 : 0.f);
    if (n0 + n + 3 < N) {
      *reinterpret_cast<float4*>(&Yt[(size_t)k * N + n0 + n]) = v;
    } else {
      float tv[4] = {v.x, v.y, v.z, v.w};
      for (int j = 0; j < 4; j++)
        if (n0 + n + j < N) Yt[(size_t)k * N + n0 + n + j] = tv[j];
    }
  }
}

// BN + ReLU flat (layer 3, node-major for pooling), H = 16
__global__ __launch_bounds__(256) void bn_apply_flat(
    const float* __restrict__ X, const float* __restrict__ ss,
    float* __restrict__ Y, int total) {
  int i = blockIdx.x * 256 + threadIdx.x;
  if (i < total) {
    int h = i & 15;
    float t = X[i] * ss[h] + ss[16 + h];
    Y[i] = t > 0.f ? t : 0.f;
  }
}

// ---------------- mean-pool + final linear ----------------
__global__ __launch_bounds__(256) void pool_kernel(
    const float* __restrict__ X, const int* __restrict__ batch,
    float* __restrict__ pool, float* __restrict__ cnt, int N) {
  __shared__ float lp[G_ * 16];
  __shared__ float lc[G_];
  int tid = threadIdx.x;
  for (int j = tid; j < G_ * 16; j += 256) lp[j] = 0.f;
  if (tid < G_) lc[tid] = 0.f;
  __syncthreads();
  int tot = N * 16;
  for (int i = blockIdx.x * 256 + tid; i < tot; i += gridDim.x * 256) {
    int n = i >> 4, h = i & 15;
    int g = batch[n];
    atomicAdd(&lp[g * 16 + h], X[i]);
    if (h == 0) atomicAdd(&lc[g], 1.0f);
  }
  __syncthreads();
  for (int j = tid; j < G_ * 16; j += 256) atomicAdd(&pool[j], lp[j]);
  if (tid < G_) atomicAdd(&cnt[tid], lc[tid]);
}

__global__ void final_linear(
    const float* __restrict__ pool, const float* __restrict__ cnt,
    const float* __restrict__ linW, const float* __restrict__ linb,
    float* __restrict__ out) {
  int g = threadIdx.x;
  if (g < G_) {
    float c = fmaxf(cnt[g], 1.0f);
    float acc = 0.f;
    for (int h = 0; h < 16; h++) acc += (pool[g * 16 + h] / c) * linW[h];
    out[g] = acc + linb[0];
  }
}

// ---------------- launch ----------------
extern "C" void kernel_launch(void* const* d_in, const int* in_sizes, int n_in,
                              void* d_out, int out_size, void* d_ws, size_t ws_size,
                              hipStream_t stream) {
  const float* x = (const float*)d_in[0];
  const int* ei = (const int*)d_in[1];
  const int* batch = (const int*)d_in[2];
  const int N = in_sizes[0] / 128;
  const int E = in_sizes[1] / 2;
  const int Etot = E + N;

  char* wsb = (char*)d_ws;
  size_t off = 0;
  auto alloc = [&](size_t bytes) -> void* {
    void* p = wsb + off;
    off += (bytes + 255) & ~(size_t)255;
    return p;
  };
  float* R0 = (float*)alloc((size_t)128 * N * 4);   // x_t / h_t / L3 BN out
  float* R1 = (float*)alloc((size_t)128 * N * 4);   // xlr
  float* R2 = (float*)alloc((size_t)64 * N * 4);    // agg out
  int* deg = (int*)alloc((size_t)N * 4);
  int* row_ptr = (int*)alloc((size_t)(N + 1) * 4);
  int* cursor = (int*)alloc((size_t)N * 4);
  int* bsums = (int*)alloc(4096);
  int* ssrc = (int*)alloc((size_t)Etot * 4);
  float* Wc1 = (float*)alloc(16384 * 4);  float* bc1 = (float*)alloc(128 * 4);
  float* Wc2 = (float*)alloc(4096 * 4);   float* bc2 = (float*)alloc(64 * 4);
  float* Wc3 = (float*)alloc(1024 * 4);   float* bc3 = (float*)alloc(32 * 4);
  float* stats = (float*)alloc(128 * 4);
  float* ss = (float*)alloc(128 * 4);
  float* pool = (float*)alloc((G_ * 16 + G_) * 4);
  float* cnt = pool + G_ * 16;

  const float* Wl1 = (const float*)d_in[3];  const float* bl1 = (const float*)d_in[4];
  const float* Wr1 = (const float*)d_in[5];  const float* br1 = (const float*)d_in[6];
  const float* att1 = (const float*)d_in[7]; const float* bias1 = (const float*)d_in[8];
  const float* g1 = (const float*)d_in[9];   const float* b1 = (const float*)d_in[10];
  const float* Wl2 = (const float*)d_in[11]; const float* bl2 = (const float*)d_in[12];
  const float* Wr2 = (const float*)d_in[13]; const float* br2 = (const float*)d_in[14];
  const float* att2 = (const float*)d_in[15]; const float* bias2 = (const float*)d_in[16];
  const float* g2 = (const float*)d_in[17];  const float* b2 = (const float*)d_in[18];
  const float* Wl3 = (const float*)d_in[19]; const float* bl3 = (const float*)d_in[20];
  const float* Wr3 = (const float*)d_in[21]; const float* br3 = (const float*)d_in[22];
  const float* att3 = (const float*)d_in[23]; const float* bias3 = (const float*)d_in[24];
  const float* g3 = (const float*)d_in[25];  const float* b3 = (const float*)d_in[26];
  const float* linW = (const float*)d_in[27]; const float* linb = (const float*)d_in[28];
  float* out = (float*)d_out;

  int ntiles = (N + 63) / 64;
  int nb = (N + 1023) / 1024;
  int nnodeblk = (N + 3) / 4;

  // pack weights
  pack_w<<<64, 256, 0, stream>>>(Wl1, Wr1, bl1, br1, Wc1, bc1, 128, 64);
  pack_w<<<16, 256, 0, stream>>>(Wl2, Wr2, bl2, br2, Wc2, bc2, 64, 32);
  pack_w<<<4, 256, 0, stream>>>(Wl3, Wr3, bl3, br3, Wc3, bc3, 32, 16);

  // transpose x -> R0 [128][N]
  transpose_nf<128><<<dim3(ntiles, 2), 256, 0, stream>>>(x, R0, N);

  // CSR build
  hipMemsetAsync(deg, 0, (size_t)N * 4, stream);
  edge_hist<<<4096, 256, 0, stream>>>(ei, deg, E, Etot);
  scan1<<<nb, 256, 0, stream>>>(deg, row_ptr, bsums, N);
  scan2<<<1, 64, 0, stream>>>(bsums, nb);
  scan3<<<(N + 255) / 256, 256, 0, stream>>>(row_ptr, cursor, bsums, N, Etot);
  scatter_edges<<<4096, 256, 0, stream>>>(ei, cursor, ssrc, E, Etot);

  // ---- layer 1 ----
  gemm_fmaj<128, 128><<<ntiles, 256, 0, stream>>>(R0, Wc1, bc1, R1, N);
  gat_agg2<64, true><<<nnodeblk, 256, 0, stream>>>(R1, att1, bias1, row_ptr, ssrc, R2, N);
  hipMemsetAsync(stats, 0, 128 * 4, stream);
  bn_stats<64><<<512, 256, 0, stream>>>(R2, stats, N);
  bn_finalize<<<1, 64, 0, stream>>>(stats, g1, b1, ss, 64, N);
  bn_apply_T<64><<<ntiles, 256, 0, stream>>>(R2, ss, R0, N);

  // ---- layer 2 ----
  gemm_fmaj<64, 64><<<ntiles, 256, 0, stream>>>(R0, Wc2, bc2, R1, N);
  gat_agg2<32, true><<<nnodeblk, 256, 0, stream>>>(R1, att2, bias2, row_ptr, ssrc, R2, N);
  hipMemsetAsync(stats, 0, 128 * 4, stream);
  bn_stats<32><<<512, 256, 0, stream>>>(R2, stats, N);
  bn_finalize<<<1, 64, 0, stream>>>(stats, g2, b2, ss, 32, N);
  bn_apply_T<32><<<ntiles, 256, 0, stream>>>(R2, ss, R0, N);

  // ---- layer 3 ----
  gemm_fmaj<32, 32><<<ntiles, 256, 0, stream>>>(R0, Wc3, bc3, R1, N);
  gat_agg2<16, false><<<nnodeblk, 256, 0, stream>>>(R1, att3, bias3, row_ptr, ssrc, R2, N);
  hipMemsetAsync(stats, 0, 128 * 4, stream);
  bn_stats<16><<<512, 256, 0, stream>>>(R2, stats, N);
  bn_finalize<<<1, 64, 0, stream>>>(stats, g3, b3, ss, 16, N);
  bn_apply_flat<<<(N * 16 + 255) / 256, 256, 0, stream>>>(R2, ss, R0, N * 16);

  // ---- pool + linear ----
  hipMemsetAsync(pool, 0, (G_ * 16 + G_) * 4, stream);
  pool_kernel<<<2048, 256, 0, stream>>>(R0, batch, pool, cnt, N);
  final_linear<<<1, 64, 0, stream>>>(pool, cnt, linW, linb, out);
}

// Round 3
// 610.150 us; speedup vs baseline: 1.4107x; 1.0941x over previous
//
#include <hip/hip_runtime.h>
#include <hip/hip_bf16.h>

// GATv2 x3 + BN + ReLU + mean-pool + linear, fp32.
// N=100000 nodes, E=1.6M edges (+N self loops), F=128, H=64/32/16, G=64.

static constexpr int G_ = 64;

// ---------------- weight packing: Wcat[k][0:H]=Wl, [H:2H]=Wr ----------------
__global__ __launch_bounds__(256) void pack_w(
    const float* __restrict__ Wl, const float* __restrict__ Wr,
    const float* __restrict__ bl, const float* __restrict__ br,
    float* __restrict__ Wcat, float* __restrict__ bcat, int FI, int H) {
  int i = blockIdx.x * 256 + threadIdx.x;
  int FO = 2 * H;
  if (i < FI * FO) {
    int k = i / FO, c = i % FO;
    Wcat[i] = (c < H) ? Wl[k * H + c] : Wr[k * H + (c - H)];
  }
  if (i < FO) bcat[i] = (i < H) ? bl[i] : br[i - H];
}

// ---------------- transpose [N][FI] -> [FI][N] ----------------
template <int FI>
__global__ __launch_bounds__(256) void transpose_nf(
    const float* __restrict__ A, float* __restrict__ At, int N) {
  __shared__ float s[64][65];
  int n0 = blockIdx.x * 64, k0 = blockIdx.y * 64;
  int tid = threadIdx.x;
  for (int idx = tid; idx < 64 * 16; idx += 256) {
    int n = idx >> 4, c = idx & 15;
    float4 v = make_float4(0.f, 0.f, 0.f, 0.f);
    if (n0 + n < N)
      v = *reinterpret_cast<const float4*>(&A[(size_t)(n0 + n) * FI + k0 + c * 4]);
    s[n][c * 4 + 0] = v.x; s[n][c * 4 + 1] = v.y;
    s[n][c * 4 + 2] = v.z; s[n][c * 4 + 3] = v.w;
  }
  __syncthreads();
  for (int idx = tid; idx < 64 * 16; idx += 256) {
    int k = idx >> 4, c = idx & 15;
    int n = c * 4;
    if (n0 + n + 3 < N) {
      float4 v = make_float4(s[n][k], s[n + 1][k], s[n + 2][k], s[n + 3][k]);
      *reinterpret_cast<float4*>(&At[(size_t)(k0 + k) * N + n0 + n]) = v;
    } else {
      for (int j = 0; j < 4; j++)
        if (n0 + n + j < N) At[(size_t)(k0 + k) * N + n0 + n + j] = s[n + j][k];
    }
  }
}

// ---------------- CSR build (XCD-partitioned by dst range) ----------------
// Partition p = dst*8/N. Block b handles partition b&7; blockIdx%8 == XCD id
// (round-robin, measured), so all atomics/stores touching a given dst come
// from ONE XCD -> lines merge in its L2 instead of bouncing via HBM.
__global__ __launch_bounds__(256) void edge_hist(
    const int* __restrict__ ei, int* __restrict__ deg, int E, int Etot, int N) {
  int p = blockIdx.x & 7;
  int q = blockIdx.x >> 3;
  int nbq = gridDim.x >> 3;
  float scale = 8.0f / (float)N;
  for (int i = q * 256 + threadIdx.x; i < Etot; i += nbq * 256) {
    int dst = (i < E) ? ei[E + i] : (i - E);
    int pp = min((int)((float)dst * scale), 7);
    if (pp == p) atomicAdd(&deg[dst], 1);
  }
}

__global__ __launch_bounds__(256) void scan1(
    const int* __restrict__ deg, int* __restrict__ part, int* __restrict__ bsums, int n) {
  __shared__ int ts[256];
  int t = threadIdx.x, b = blockIdx.x;
  int base = b * 1024 + t * 4;
  int d[4];
#pragma unroll
  for (int q = 0; q < 4; q++) d[q] = (base + q < n) ? deg[base + q] : 0;
  int s = d[0] + d[1] + d[2] + d[3];
  ts[t] = s;
  __syncthreads();
  for (int o = 1; o < 256; o <<= 1) {
    int v = (t >= o) ? ts[t - o] : 0;
    __syncthreads();
    ts[t] += v;
    __syncthreads();
  }
  int incl = ts[t];
  if (t == 255) bsums[b] = incl;
  int run = incl - s;
#pragma unroll
  for (int q = 0; q < 4; q++) {
    if (base + q < n) part[base + q] = run;
    run += d[q];
  }
}

__global__ void scan2(int* bsums, int nb) {
  if (threadIdx.x == 0 && blockIdx.x == 0) {
    int r = 0;
    for (int i = 0; i < nb; i++) { int t = bsums[i]; bsums[i] = r; r += t; }
  }
}

__global__ __launch_bounds__(256) void scan3(
    int* __restrict__ rp, int* __restrict__ cur, const int* __restrict__ bsums,
    int n, int Etot) {
  int i = blockIdx.x * 256 + threadIdx.x;
  if (i < n) {
    int v = rp[i] + bsums[i >> 10];
    rp[i] = v; cur[i] = v;
  }
  if (i == 0) rp[n] = Etot;
}

__global__ __launch_bounds__(256) void scatter_edges(
    const int* __restrict__ ei, int* __restrict__ cur, int* __restrict__ ssrc,
    int E, int Etot, int N) {
  int p = blockIdx.x & 7;
  int q = blockIdx.x >> 3;
  int nbq = gridDim.x >> 3;
  float scale = 8.0f / (float)N;
  for (int i = q * 256 + threadIdx.x; i < Etot; i += nbq * 256) {
    int dst = (i < E) ? ei[E + i] : (i - E);
    int pp = min((int)((float)dst * scale), 7);
    if (pp != p) continue;
    int src = (i < E) ? ei[i] : (i - E);
    int pos = atomicAdd(&cur[dst], 1);
    ssrc[pos] = src;
  }
}

// ---------------- GEMM: C[N][FO] = At^T[N][FI] @ Wcat[FI][FO] + bcat ----------------
template <int FI, int FO>
__global__ __launch_bounds__(256) void gemm_fmaj(
    const float* __restrict__ At, const float* __restrict__ Wcat,
    const float* __restrict__ bcat, float* __restrict__ C, int N) {
  constexpr int KC = 32;
  constexpr int HP = FO / 16;
  __shared__ float As[FI * 64];
  __shared__ float Ws[KC * FO];
  int tid = threadIdx.x;
  int ng = tid & 15, hg = tid >> 4;
  int n0 = blockIdx.x * 64;

  if (n0 + 64 <= N) {
    for (int idx = tid; idx < FI * 16; idx += 256) {
      int k = idx >> 4, c = idx & 15;
      *reinterpret_cast<float4*>(&As[k * 64 + c * 4]) =
          *reinterpret_cast<const float4*>(&At[(size_t)k * N + n0 + c * 4]);
    }
  } else {
    for (int idx = tid; idx < FI * 64; idx += 256) {
      int k = idx >> 6, nn = idx & 63;
      As[k * 64 + nn] = (n0 + nn < N) ? At[(size_t)k * N + n0 + nn] : 0.f;
    }
  }

  float acc[4][HP];
#pragma unroll
  for (int i = 0; i < 4; i++)
#pragma unroll
    for (int j = 0; j < HP; j++) acc[i][j] = 0.f;

  for (int kc = 0; kc < FI; kc += KC) {
    __syncthreads();
    for (int idx = tid; idx < KC * FO / 4; idx += 256)
      *reinterpret_cast<float4*>(&Ws[idx * 4]) =
          *reinterpret_cast<const float4*>(&Wcat[kc * FO + idx * 4]);
    __syncthreads();
#pragma unroll
    for (int kk = 0; kk < KC; kk++) {
      float a_[4];
#pragma unroll
      for (int i = 0; i < 4; i++) a_[i] = As[(kc + kk) * 64 + ng * 4 + i];
      float w_[HP];
#pragma unroll
      for (int j = 0; j < HP; j++) w_[j] = Ws[kk * FO + hg * HP + j];
#pragma unroll
      for (int i = 0; i < 4; i++)
#pragma unroll
        for (int j = 0; j < HP; j++) acc[i][j] += a_[i] * w_[j];
    }
  }

#pragma unroll
  for (int i = 0; i < 4; i++) {
    int n = n0 + ng * 4 + i;
    if (n < N) {
#pragma unroll
      for (int j = 0; j < HP; j++)
        C[(size_t)n * FO + hg * HP + j] = acc[i][j] + bcat[hg * HP + j];
    }
  }
}

// ---------------- GATv2 aggregation v2 ----------------
__device__ __forceinline__ float lrelu02(float z) {
  return (z > 0.f) ? z : 0.2f * z;
}

template <int H, bool UN2>
__global__ __launch_bounds__(256) void gat_agg2(
    const float* __restrict__ xlr, const float* __restrict__ att,
    const float* __restrict__ bias, const int* __restrict__ rp,
    const int* __restrict__ ssrc, float* __restrict__ out, int N) {
  constexpr int L = H / 4;    // lanes per edge
  constexpr int C = 64 / L;   // concurrent edges per wave
  int v = blockIdx.x * 4 + (threadIdx.x >> 6);
  if (v >= N) return;
  int lane = threadIdx.x & 63;
  int fl = lane % L;
  int sub = lane / L;

  const float4 xr4 = *reinterpret_cast<const float4*>(&xlr[(size_t)v * (2 * H) + H + fl * 4]);
  const float4 a4 = *reinterpret_cast<const float4*>(&att[fl * 4]);
  int beg = rp[v], end = rp[v + 1];

  float mA = -3.0e38f, dA = 0.f;
  float4 accA = make_float4(0.f, 0.f, 0.f, 0.f);
  float mB = -3.0e38f, dB = 0.f;
  float4 accB = make_float4(0.f, 0.f, 0.f, 0.f);

  constexpr int STEP = UN2 ? 2 * C : C;

  for (int j = beg + sub; j < end; j += STEP) {
    {
      int u = ssrc[j];
      float4 xl4 = *reinterpret_cast<const float4*>(&xlr[(size_t)u * (2 * H) + fl * 4]);
      float t = a4.x * lrelu02(xl4.x + xr4.x);
      t = fmaf(a4.y, lrelu02(xl4.y + xr4.y), t);
      t = fmaf(a4.z, lrelu02(xl4.z + xr4.z), t);
      t = fmaf(a4.w, lrelu02(xl4.w + xr4.w), t);
#pragma unroll
      for (int o = L / 2; o >= 1; o >>= 1) t += __shfl_xor(t, o);
      float mn = fmaxf(mA, t);
      float sc = __expf(mA - mn);
      float w = __expf(t - mn);
      dA = dA * sc + w;
      accA.x = fmaf(w, xl4.x, accA.x * sc);
      accA.y = fmaf(w, xl4.y, accA.y * sc);
      accA.z = fmaf(w, xl4.z, accA.z * sc);
      accA.w = fmaf(w, xl4.w, accA.w * sc);
      mA = mn;
    }
    if (UN2) {
      int j2 = j + C;
      if (j2 < end) {
        int u = ssrc[j2];
        float4 xl4 = *reinterpret_cast<const float4*>(&xlr[(size_t)u * (2 * H) + fl * 4]);
        float t = a4.x * lrelu02(xl4.x + xr4.x);
        t = fmaf(a4.y, lrelu02(xl4.y + xr4.y), t);
        t = fmaf(a4.z, lrelu02(xl4.z + xr4.z), t);
        t = fmaf(a4.w, lrelu02(xl4.w + xr4.w), t);
#pragma unroll
        for (int o = L / 2; o >= 1; o >>= 1) t += __shfl_xor(t, o);
        float mn = fmaxf(mB, t);
        float sc = __expf(mB - mn);
        float w = __expf(t - mn);
        dB = dB * sc + w;
        accB.x = fmaf(w, xl4.x, accB.x * sc);
        accB.y = fmaf(w, xl4.y, accB.y * sc);
        accB.z = fmaf(w, xl4.z, accB.z * sc);
        accB.w = fmaf(w, xl4.w, accB.w * sc);
        mB = mn;
      }
    }
  }

  if (UN2) {
    float mn = fmaxf(mA, mB);
    float s1 = __expf(mA - mn), s2 = __expf(mB - mn);
    dA = dA * s1 + dB * s2;
    accA.x = accA.x * s1 + accB.x * s2;
    accA.y = accA.y * s1 + accB.y * s2;
    accA.z = accA.z * s1 + accB.z * s2;
    accA.w = accA.w * s1 + accB.w * s2;
    mA = mn;
  }

#pragma unroll
  for (int o = L; o < 64; o <<= 1) {
    float mo = __shfl_xor(mA, o);
    float d2 = __shfl_xor(dA, o);
    float ax = __shfl_xor(accA.x, o);
    float ay = __shfl_xor(accA.y, o);
    float az = __shfl_xor(accA.z, o);
    float aw = __shfl_xor(accA.w, o);
    float mn = fmaxf(mA, mo);
    float s1 = __expf(mA - mn), s2 = __expf(mo - mn);
    dA = dA * s1 + d2 * s2;
    accA.x = accA.x * s1 + ax * s2;
    accA.y = accA.y * s1 + ay * s2;
    accA.z = accA.z * s1 + az * s2;
    accA.w = accA.w * s1 + aw * s2;
    mA = mn;
  }

  if (lane < L) {
    float inv = 1.f / (dA + 1e-16f);
    const float4 b4 = *reinterpret_cast<const float4*>(&bias[fl * 4]);
    float4 o4 = make_float4(fmaf(accA.x, inv, b4.x), fmaf(accA.y, inv, b4.y),
                            fmaf(accA.z, inv, b4.z), fmaf(accA.w, inv, b4.w));
    *reinterpret_cast<float4*>(&out[(size_t)v * H + fl * 4]) = o4;
  }
}

// ---------------- BatchNorm ----------------
template <int H>
__global__ __launch_bounds__(256) void bn_stats(
    const float* __restrict__ X, float* __restrict__ stats, int N) {
  __shared__ float ls[256], ls2[256];
  int tid = threadIdx.x;
  int h = tid % H;
  constexpr int RPB = 256 / H;
  int r0 = blockIdx.x * RPB + tid / H;
  float s = 0.f, s2 = 0.f;
  for (int n = r0; n < N; n += gridDim.x * RPB) {
    float val = X[(size_t)n * H + h];
    s += val; s2 += val * val;
  }
  ls[tid] = s; ls2[tid] = s2;
  __syncthreads();
  if (tid < H) {
    for (int g = 1; g < RPB; g++) { s += ls[tid + g * H]; s2 += ls2[tid + g * H]; }
    atomicAdd(&stats[h], s);
    atomicAdd(&stats[H + h], s2);
  }
}

__global__ void bn_finalize(
    const float* __restrict__ stats, const float* __restrict__ gamma,
    const float* __restrict__ beta, float* __restrict__ ss, int H, int N) {
  int h = threadIdx.x;
  if (h < H) {
    float mean = stats[h] / (float)N;
    float var = stats[H + h] / (float)N - mean * mean;
    float istd = rsqrtf(var + 1e-5f);
    float sc = gamma[h] * istd;
    ss[h] = sc;
    ss[H + h] = beta[h] - mean * sc;
  }
}

// BN + ReLU, write transposed [H][N] (layers 1,2 feed the next GEMM)
template <int H>
__global__ __launch_bounds__(256) void bn_apply_T(
    const float* __restrict__ X, const float* __restrict__ ss,
    float* __restrict__ Yt, int N) {
  __shared__ float s[64][65];
  int n0 = blockIdx.x * 64;
  int tid = threadIdx.x;
  for (int idx = tid; idx < 64 * (H / 4); idx += 256) {
    int n = idx / (H / 4), c = idx % (H / 4);
    float4 v = make_float4(0.f, 0.f, 0.f, 0.f);
    if (n0 + n < N)
      v = *reinterpret_cast<const float4*>(&X[(size_t)(n0 + n) * H + c * 4]);
    s[n][c * 4 + 0] = v.x; s[n][c * 4 + 1] = v.y;
    s[n][c * 4 + 2] = v.z; s[n][c * 4 + 3] = v.w;
  }
  __syncthreads();
  for (int idx = tid; idx < H * 16; idx += 256) {
    int k = idx >> 4, c = idx & 15;
    int n = c * 4;
    float sc = ss[k], sh = ss[H + k];
    float t0 = s[n + 0][k] * sc + sh;
    float t1 = s[n + 1][k] * sc + sh;
    float t2 = s[n + 2][k] * sc + sh;
    float t3 = s[n + 3][k] * sc + sh;
    float4 v = make_float4(t0 > 0.f ? t0 : 0.f, t1 > 0.f ? t1 : 0.f,
                           t2 > 0.f ? t2 : 0.f, t3 > 0.f ? t3 : 0.f);
    if (n0 + n + 3 < N) {
      *reinterpret_cast<float4*>(&Yt[(size_t)k * N + n0 + n]) = v;
    } else {
      float tv[4] = {v.x, v.y, v.z, v.w};
      for (int j = 0; j < 4; j++)
        if (n0 + n + j < N) Yt[(size_t)k * N + n0 + n + j] = tv[j];
    }
  }
}

// BN + ReLU flat (layer 3, node-major for pooling), H = 16
__global__ __launch_bounds__(256) void bn_apply_flat(
    const float* __restrict__ X, const float* __restrict__ ss,
    float* __restrict__ Y, int total) {
  int i = blockIdx.x * 256 + threadIdx.x;
  if (i < total) {
    int h = i & 15;
    float t = X[i] * ss[h] + ss[16 + h];
    Y[i] = t > 0.f ? t : 0.f;
  }
}

// ---------------- mean-pool + final linear ----------------
__global__ __launch_bounds__(256) void pool_kernel(
    const float* __restrict__ X, const int* __restrict__ batch,
    float* __restrict__ pool, float* __restrict__ cnt, int N) {
  __shared__ float lp[G_ * 16];
  __shared__ float lc[G_];
  int tid = threadIdx.x;
  for (int j = tid; j < G_ * 16; j += 256) lp[j] = 0.f;
  if (tid < G_) lc[tid] = 0.f;
  __syncthreads();
  int tot = N * 16;
  for (int i = blockIdx.x * 256 + tid; i < tot; i += gridDim.x * 256) {
    int n = i >> 4, h = i & 15;
    int g = batch[n];
    atomicAdd(&lp[g * 16 + h], X[i]);
    if (h == 0) atomicAdd(&lc[g], 1.0f);
  }
  __syncthreads();
  for (int j = tid; j < G_ * 16; j += 256) atomicAdd(&pool[j], lp[j]);
  if (tid < G_) atomicAdd(&cnt[tid], lc[tid]);
}

__global__ void final_linear(
    const float* __restrict__ pool, const float* __restrict__ cnt,
    const float* __restrict__ linW, const float* __restrict__ linb,
    float* __restrict__ out) {
  int g = threadIdx.x;
  if (g < G_) {
    float c = fmaxf(cnt[g], 1.0f);
    float acc = 0.f;
    for (int h = 0; h < 16; h++) acc += (pool[g * 16 + h] / c) * linW[h];
    out[g] = acc + linb[0];
  }
}

// ---------------- launch ----------------
extern "C" void kernel_launch(void* const* d_in, const int* in_sizes, int n_in,
                              void* d_out, int out_size, void* d_ws, size_t ws_size,
                              hipStream_t stream) {
  const float* x = (const float*)d_in[0];
  const int* ei = (const int*)d_in[1];
  const int* batch = (const int*)d_in[2];
  const int N = in_sizes[0] / 128;
  const int E = in_sizes[1] / 2;
  const int Etot = E + N;

  char* wsb = (char*)d_ws;
  size_t off = 0;
  auto alloc = [&](size_t bytes) -> void* {
    void* p = wsb + off;
    off += (bytes + 255) & ~(size_t)255;
    return p;
  };
  float* R0 = (float*)alloc((size_t)128 * N * 4);   // x_t / h_t / L3 BN out
  float* R1 = (float*)alloc((size_t)128 * N * 4);   // xlr
  float* R2 = (float*)alloc((size_t)64 * N * 4);    // agg out
  int* deg = (int*)alloc((size_t)N * 4);
  int* row_ptr = (int*)alloc((size_t)(N + 1) * 4);
  int* cursor = (int*)alloc((size_t)N * 4);
  int* bsums = (int*)alloc(4096);
  int* ssrc = (int*)alloc((size_t)Etot * 4);
  float* Wc1 = (float*)alloc(16384 * 4);  float* bc1 = (float*)alloc(128 * 4);
  float* Wc2 = (float*)alloc(4096 * 4);   float* bc2 = (float*)alloc(64 * 4);
  float* Wc3 = (float*)alloc(1024 * 4);   float* bc3 = (float*)alloc(32 * 4);
  float* stats = (float*)alloc(128 * 4);
  float* ss = (float*)alloc(128 * 4);
  float* pool = (float*)alloc((G_ * 16 + G_) * 4);
  float* cnt = pool + G_ * 16;

  const float* Wl1 = (const float*)d_in[3];  const float* bl1 = (const float*)d_in[4];
  const float* Wr1 = (const float*)d_in[5];  const float* br1 = (const float*)d_in[6];
  const float* att1 = (const float*)d_in[7]; const float* bias1 = (const float*)d_in[8];
  const float* g1 = (const float*)d_in[9];   const float* b1 = (const float*)d_in[10];
  const float* Wl2 = (const float*)d_in[11]; const float* bl2 = (const float*)d_in[12];
  const float* Wr2 = (const float*)d_in[13]; const float* br2 = (const float*)d_in[14];
  const float* att2 = (const float*)d_in[15]; const float* bias2 = (const float*)d_in[16];
  const float* g2 = (const float*)d_in[17];  const float* b2 = (const float*)d_in[18];
  const float* Wl3 = (const float*)d_in[19]; const float* bl3 = (const float*)d_in[20];
  const float* Wr3 = (const float*)d_in[21]; const float* br3 = (const float*)d_in[22];
  const float* att3 = (const float*)d_in[23]; const float* bias3 = (const float*)d_in[24];
  const float* g3 = (const float*)d_in[25];  const float* b3 = (const float*)d_in[26];
  const float* linW = (const float*)d_in[27]; const float* linb = (const float*)d_in[28];
  float* out = (float*)d_out;

  int ntiles = (N + 63) / 64;
  int nb = (N + 1023) / 1024;
  int nnodeblk = (N + 3) / 4;

  // pack weights
  pack_w<<<64, 256, 0, stream>>>(Wl1, Wr1, bl1, br1, Wc1, bc1, 128, 64);
  pack_w<<<16, 256, 0, stream>>>(Wl2, Wr2, bl2, br2, Wc2, bc2, 64, 32);
  pack_w<<<4, 256, 0, stream>>>(Wl3, Wr3, bl3, br3, Wc3, bc3, 32, 16);

  // transpose x -> R0 [128][N]
  transpose_nf<128><<<dim3(ntiles, 2), 256, 0, stream>>>(x, R0, N);

  // CSR build (XCD-partitioned hist + scatter)
  hipMemsetAsync(deg, 0, (size_t)N * 4, stream);
  edge_hist<<<4096, 256, 0, stream>>>(ei, deg, E, Etot, N);
  scan1<<<nb, 256, 0, stream>>>(deg, row_ptr, bsums, N);
  scan2<<<1, 64, 0, stream>>>(bsums, nb);
  scan3<<<(N + 255) / 256, 256, 0, stream>>>(row_ptr, cursor, bsums, N, Etot);
  scatter_edges<<<4096, 256, 0, stream>>>(ei, cursor, ssrc, E, Etot, N);

  // ---- layer 1 ----
  gemm_fmaj<128, 128><<<ntiles, 256, 0, stream>>>(R0, Wc1, bc1, R1, N);
  gat_agg2<64, true><<<nnodeblk, 256, 0, stream>>>(R1, att1, bias1, row_ptr, ssrc, R2, N);
  hipMemsetAsync(stats, 0, 128 * 4, stream);
  bn_stats<64><<<512, 256, 0, stream>>>(R2, stats, N);
  bn_finalize<<<1, 64, 0, stream>>>(stats, g1, b1, ss, 64, N);
  bn_apply_T<64><<<ntiles, 256, 0, stream>>>(R2, ss, R0, N);

  // ---- layer 2 ----
  gemm_fmaj<64, 64><<<ntiles, 256, 0, stream>>>(R0, Wc2, bc2, R1, N);
  gat_agg2<32, true><<<nnodeblk, 256, 0, stream>>>(R1, att2, bias2, row_ptr, ssrc, R2, N);
  hipMemsetAsync(stats, 0, 128 * 4, stream);
  bn_stats<32><<<512, 256, 0, stream>>>(R2, stats, N);
  bn_finalize<<<1, 64, 0, stream>>>(stats, g2, b2, ss, 32, N);
  bn_apply_T<32><<<ntiles, 256, 0, stream>>>(R2, ss, R0, N);

  // ---- layer 3 ----
  gemm_fmaj<32, 32><<<ntiles, 256, 0, stream>>>(R0, Wc3, bc3, R1, N);
  gat_agg2<16, false><<<nnodeblk, 256, 0, stream>>>(R1, att3, bias3, row_ptr, ssrc, R2, N);
  hipMemsetAsync(stats, 0, 128 * 4, stream);
  bn_stats<16><<<512, 256, 0, stream>>>(R2, stats, N);
  bn_finalize<<<1, 64, 0, stream>>>(stats, g3, b3, ss, 16, N);
  bn_apply_flat<<<(N * 16 + 255) / 256, 256, 0, stream>>>(R2, ss, R0, N * 16);

  // ---- pool + linear ----
  hipMemsetAsync(pool, 0, (G_ * 16 + G_) * 4, stream);
  pool_kernel<<<2048, 256, 0, stream>>>(R0, batch, pool, cnt, N);
  final_linear<<<1, 64, 0, stream>>>(pool, cnt, linW, linb, out);
}

// Round 4
// 603.692 us; speedup vs baseline: 1.4258x; 1.0107x over previous
//
#include <hip/hip_runtime.h>
#include <hip/hip_bf16.h>

// GATv2 x3 + BN + ReLU + mean-pool + linear, fp32.
// N=100000 nodes, E=1.6M edges (+N self loops), F=128, H=64/32/16, G=64.

static constexpr int G_ = 64;

// ---------------- weight packing: Wcat[k][0:H]=Wl, [H:2H]=Wr ----------------
__global__ __launch_bounds__(256) void pack_w(
    const float* __restrict__ Wl, const float* __restrict__ Wr,
    const float* __restrict__ bl, const float* __restrict__ br,
    float* __restrict__ Wcat, float* __restrict__ bcat, int FI, int H) {
  int i = blockIdx.x * 256 + threadIdx.x;
  int FO = 2 * H;
  if (i < FI * FO) {
    int k = i / FO, c = i % FO;
    Wcat[i] = (c < H) ? Wl[k * H + c] : Wr[k * H + (c - H)];
  }
  if (i < FO) bcat[i] = (i < H) ? bl[i] : br[i - H];
}

// ---------------- transpose [N][FI] -> [FI][N] ----------------
template <int FI>
__global__ __launch_bounds__(256) void transpose_nf(
    const float* __restrict__ A, float* __restrict__ At, int N) {
  __shared__ float s[64][65];
  int n0 = blockIdx.x * 64, k0 = blockIdx.y * 64;
  int tid = threadIdx.x;
  for (int idx = tid; idx < 64 * 16; idx += 256) {
    int n = idx >> 4, c = idx & 15;
    float4 v = make_float4(0.f, 0.f, 0.f, 0.f);
    if (n0 + n < N)
      v = *reinterpret_cast<const float4*>(&A[(size_t)(n0 + n) * FI + k0 + c * 4]);
    s[n][c * 4 + 0] = v.x; s[n][c * 4 + 1] = v.y;
    s[n][c * 4 + 2] = v.z; s[n][c * 4 + 3] = v.w;
  }
  __syncthreads();
  for (int idx = tid; idx < 64 * 16; idx += 256) {
    int k = idx >> 4, c = idx & 15;
    int n = c * 4;
    if (n0 + n + 3 < N) {
      float4 v = make_float4(s[n][k], s[n + 1][k], s[n + 2][k], s[n + 3][k]);
      *reinterpret_cast<float4*>(&At[(size_t)(k0 + k) * N + n0 + n]) = v;
    } else {
      for (int j = 0; j < 4; j++)
        if (n0 + n + j < N) At[(size_t)(k0 + k) * N + n0 + n + j] = s[n + j][k];
    }
  }
}

// ---------------- CSR build (XCD-partitioned by dst range) ----------------
__global__ __launch_bounds__(256) void edge_hist(
    const int* __restrict__ ei, int* __restrict__ deg, int E, int Etot, int N) {
  int p = blockIdx.x & 7;
  int q = blockIdx.x >> 3;
  int nbq = gridDim.x >> 3;
  float scale = 8.0f / (float)N;
  for (int i = q * 256 + threadIdx.x; i < Etot; i += nbq * 256) {
    int dst = (i < E) ? ei[E + i] : (i - E);
    int pp = min((int)((float)dst * scale), 7);
    if (pp == p) atomicAdd(&deg[dst], 1);
  }
}

__global__ __launch_bounds__(256) void scan1(
    const int* __restrict__ deg, int* __restrict__ part, int* __restrict__ bsums, int n) {
  __shared__ int ts[256];
  int t = threadIdx.x, b = blockIdx.x;
  int base = b * 1024 + t * 4;
  int d[4];
#pragma unroll
  for (int q = 0; q < 4; q++) d[q] = (base + q < n) ? deg[base + q] : 0;
  int s = d[0] + d[1] + d[2] + d[3];
  ts[t] = s;
  __syncthreads();
  for (int o = 1; o < 256; o <<= 1) {
    int v = (t >= o) ? ts[t - o] : 0;
    __syncthreads();
    ts[t] += v;
    __syncthreads();
  }
  int incl = ts[t];
  if (t == 255) bsums[b] = incl;
  int run = incl - s;
#pragma unroll
  for (int q = 0; q < 4; q++) {
    if (base + q < n) part[base + q] = run;
    run += d[q];
  }
}

__global__ void scan2(int* bsums, int nb) {
  if (threadIdx.x == 0 && blockIdx.x == 0) {
    int r = 0;
    for (int i = 0; i < nb; i++) { int t = bsums[i]; bsums[i] = r; r += t; }
  }
}

__global__ __launch_bounds__(256) void scan3(
    int* __restrict__ rp, int* __restrict__ cur, const int* __restrict__ bsums,
    int n, int Etot) {
  int i = blockIdx.x * 256 + threadIdx.x;
  if (i < n) {
    int v = rp[i] + bsums[i >> 10];
    rp[i] = v; cur[i] = v;
  }
  if (i == 0) rp[n] = Etot;
}

__global__ __launch_bounds__(256) void scatter_edges(
    const int* __restrict__ ei, int* __restrict__ cur, int* __restrict__ ssrc,
    int E, int Etot, int N) {
  int p = blockIdx.x & 7;
  int q = blockIdx.x >> 3;
  int nbq = gridDim.x >> 3;
  float scale = 8.0f / (float)N;
  for (int i = q * 256 + threadIdx.x; i < Etot; i += nbq * 256) {
    int dst = (i < E) ? ei[E + i] : (i - E);
    int pp = min((int)((float)dst * scale), 7);
    if (pp != p) continue;
    int src = (i < E) ? ei[i] : (i - E);
    int pos = atomicAdd(&cur[dst], 1);
    ssrc[pos] = src;
  }
}

// ---------------- GEMM v2: C[N][FO] = At^T[N][FI] @ Wcat[FI][FO] + bcat ----
// 128-node x FO block tile, 8x8 (8 x FO/16) register tile, KC=32 chunks.
// A-frag: 2x ds_read_b128 at nodes {4ng, 64+4ng} (2-way alias = free).
// W-frag: wave-broadcast (4 distinct addresses per wave).
template <int FI, int FO>
__global__ __launch_bounds__(256) void gemm_fmaj2(
    const float* __restrict__ At, const float* __restrict__ Wcat,
    const float* __restrict__ bcat, float* __restrict__ C, int N) {
  constexpr int KC = 32;
  constexpr int CT = FO / 16;  // cols per thread: 8 / 4 / 2
  __shared__ float As[KC * 128];
  __shared__ float Ws[KC * FO];
  int tid = threadIdx.x;
  int ng = tid & 15;   // node group
  int hg = tid >> 4;   // col group (16)
  int n0 = blockIdx.x * 128;
  bool full = (n0 + 128 <= N);

  float acc[8][CT];
#pragma unroll
  for (int i = 0; i < 8; i++)
#pragma unroll
    for (int j = 0; j < CT; j++) acc[i][j] = 0.f;

  for (int kc = 0; kc < FI; kc += KC) {
    __syncthreads();
    // stage As: KC rows x 128 nodes
    {
      int r = tid >> 5;          // 0..7
      int c = (tid & 31) * 4;    // 0..124
      for (int rr = r; rr < KC; rr += 8) {
        float4 v;
        if (full) {
          v = *reinterpret_cast<const float4*>(&At[(size_t)(kc + rr) * N + n0 + c]);
        } else {
          float tmp[4];
#pragma unroll
          for (int j = 0; j < 4; j++)
            tmp[j] = (n0 + c + j < N) ? At[(size_t)(kc + rr) * N + n0 + c + j] : 0.f;
          v = make_float4(tmp[0], tmp[1], tmp[2], tmp[3]);
        }
        *reinterpret_cast<float4*>(&As[rr * 128 + c]) = v;
      }
    }
    // stage Ws: KC x FO
    for (int idx = tid; idx < KC * FO / 4; idx += 256)
      *reinterpret_cast<float4*>(&Ws[idx * 4]) =
          *reinterpret_cast<const float4*>(&Wcat[kc * FO + idx * 4]);
    __syncthreads();
#pragma unroll
    for (int kk = 0; kk < KC; kk++) {
      float4 alo = *reinterpret_cast<float4*>(&As[kk * 128 + 4 * ng]);
      float4 ahi = *reinterpret_cast<float4*>(&As[kk * 128 + 64 + 4 * ng]);
      float a[8] = {alo.x, alo.y, alo.z, alo.w, ahi.x, ahi.y, ahi.z, ahi.w};
      float w[CT];
#pragma unroll
      for (int j = 0; j < CT; j++) w[j] = Ws[kk * FO + hg * CT + j];
#pragma unroll
      for (int i = 0; i < 8; i++)
#pragma unroll
        for (int j = 0; j < CT; j++) acc[i][j] = fmaf(a[i], w[j], acc[i][j]);
    }
  }

  float b[CT];
#pragma unroll
  for (int j = 0; j < CT; j++) b[j] = bcat[hg * CT + j];
#pragma unroll
  for (int i = 0; i < 8; i++) {
    int n = n0 + ((i < 4) ? (4 * ng + i) : (64 + 4 * ng + (i - 4)));
    if (n < N) {
#pragma unroll
      for (int j = 0; j < CT; j++)
        C[(size_t)n * FO + hg * CT + j] = acc[i][j] + b[j];
    }
  }
}

// ---------------- GATv2 aggregation v3: defer-max online softmax ----------
__device__ __forceinline__ float lrelu02(float z) {
  return (z > 0.f) ? z : 0.2f * z;
}

template <int H, bool UN2>
__global__ __launch_bounds__(256) void gat_agg2(
    const float* __restrict__ xlr, const float* __restrict__ att,
    const float* __restrict__ bias, const int* __restrict__ rp,
    const int* __restrict__ ssrc, float* __restrict__ out, int N) {
  constexpr int L = H / 4;    // lanes per edge
  constexpr int C = 64 / L;   // concurrent edges per wave
  int v = blockIdx.x * 4 + (threadIdx.x >> 6);
  if (v >= N) return;
  int lane = threadIdx.x & 63;
  int fl = lane % L;
  int sub = lane / L;

  const float4 xr4 = *reinterpret_cast<const float4*>(&xlr[(size_t)v * (2 * H) + H + fl * 4]);
  const float4 a4 = *reinterpret_cast<const float4*>(&att[fl * 4]);
  int beg = rp[v], end = rp[v + 1];

  float mA = -3.0e38f, dA = 0.f;
  float4 accA = make_float4(0.f, 0.f, 0.f, 0.f);
  float mB = -3.0e38f, dB = 0.f;
  float4 accB = make_float4(0.f, 0.f, 0.f, 0.f);

  constexpr int STEP = UN2 ? 2 * C : C;

  for (int j = beg + sub; j < end; j += STEP) {
    {
      int u = ssrc[j];
      float4 xl4 = *reinterpret_cast<const float4*>(&xlr[(size_t)u * (2 * H) + fl * 4]);
      float t = a4.x * lrelu02(xl4.x + xr4.x);
      t = fmaf(a4.y, lrelu02(xl4.y + xr4.y), t);
      t = fmaf(a4.z, lrelu02(xl4.z + xr4.z), t);
      t = fmaf(a4.w, lrelu02(xl4.w + xr4.w), t);
#pragma unroll
      for (int o = L / 2; o >= 1; o >>= 1) t += __shfl_xor(t, o);
      float diff = t - mA;
      if (diff > 8.f) {  // rare rescale (uniform across the L-lane subgroup)
        float sc = __expf(-diff);
        dA *= sc;
        accA.x *= sc; accA.y *= sc; accA.z *= sc; accA.w *= sc;
        mA = t; diff = 0.f;
      }
      float w = __expf(diff);
      dA += w;
      accA.x = fmaf(w, xl4.x, accA.x);
      accA.y = fmaf(w, xl4.y, accA.y);
      accA.z = fmaf(w, xl4.z, accA.z);
      accA.w = fmaf(w, xl4.w, accA.w);
    }
    if (UN2) {
      int j2 = j + C;
      if (j2 < end) {
        int u = ssrc[j2];
        float4 xl4 = *reinterpret_cast<const float4*>(&xlr[(size_t)u * (2 * H) + fl * 4]);
        float t = a4.x * lrelu02(xl4.x + xr4.x);
        t = fmaf(a4.y, lrelu02(xl4.y + xr4.y), t);
        t = fmaf(a4.z, lrelu02(xl4.z + xr4.z), t);
        t = fmaf(a4.w, lrelu02(xl4.w + xr4.w), t);
#pragma unroll
        for (int o = L / 2; o >= 1; o >>= 1) t += __shfl_xor(t, o);
        float diff = t - mB;
        if (diff > 8.f) {
          float sc = __expf(-diff);
          dB *= sc;
          accB.x *= sc; accB.y *= sc; accB.z *= sc; accB.w *= sc;
          mB = t; diff = 0.f;
        }
        float w = __expf(diff);
        dB += w;
        accB.x = fmaf(w, xl4.x, accB.x);
        accB.y = fmaf(w, xl4.y, accB.y);
        accB.z = fmaf(w, xl4.z, accB.z);
        accB.w = fmaf(w, xl4.w, accB.w);
      }
    }
  }

  if (UN2) {
    float mn = fmaxf(mA, mB);
    float s1 = __expf(mA - mn), s2 = __expf(mB - mn);
    dA = dA * s1 + dB * s2;
    accA.x = accA.x * s1 + accB.x * s2;
    accA.y = accA.y * s1 + accB.y * s2;
    accA.z = accA.z * s1 + accB.z * s2;
    accA.w = accA.w * s1 + accB.w * s2;
    mA = mn;
  }

#pragma unroll
  for (int o = L; o < 64; o <<= 1) {
    float mo = __shfl_xor(mA, o);
    float d2 = __shfl_xor(dA, o);
    float ax = __shfl_xor(accA.x, o);
    float ay = __shfl_xor(accA.y, o);
    float az = __shfl_xor(accA.z, o);
    float aw = __shfl_xor(accA.w, o);
    float mn = fmaxf(mA, mo);
    float s1 = __expf(mA - mn), s2 = __expf(mo - mn);
    dA = dA * s1 + d2 * s2;
    accA.x = accA.x * s1 + ax * s2;
    accA.y = accA.y * s1 + ay * s2;
    accA.z = accA.z * s1 + az * s2;
    accA.w = accA.w * s1 + aw * s2;
    mA = mn;
  }

  if (lane < L) {
    float inv = 1.f / (dA + 1e-16f);
    const float4 b4 = *reinterpret_cast<const float4*>(&bias[fl * 4]);
    float4 o4 = make_float4(fmaf(accA.x, inv, b4.x), fmaf(accA.y, inv, b4.y),
                            fmaf(accA.z, inv, b4.z), fmaf(accA.w, inv, b4.w));
    *reinterpret_cast<float4*>(&out[(size_t)v * H + fl * 4]) = o4;
  }
}

// ---------------- BatchNorm ----------------
template <int H>
__global__ __launch_bounds__(256) void bn_stats(
    const float* __restrict__ X, float* __restrict__ stats, int N) {
  __shared__ float ls[256], ls2[256];
  int tid = threadIdx.x;
  int h = tid % H;
  constexpr int RPB = 256 / H;
  int r0 = blockIdx.x * RPB + tid / H;
  float s = 0.f, s2 = 0.f;
  for (int n = r0; n < N; n += gridDim.x * RPB) {
    float val = X[(size_t)n * H + h];
    s += val; s2 += val * val;
  }
  ls[tid] = s; ls2[tid] = s2;
  __syncthreads();
  if (tid < H) {
    for (int g = 1; g < RPB; g++) { s += ls[tid + g * H]; s2 += ls2[tid + g * H]; }
    atomicAdd(&stats[h], s);
    atomicAdd(&stats[H + h], s2);
  }
}

__global__ void bn_finalize(
    const float* __restrict__ stats, const float* __restrict__ gamma,
    const float* __restrict__ beta, float* __restrict__ ss, int H, int N) {
  int h = threadIdx.x;
  if (h < H) {
    float mean = stats[h] / (float)N;
    float var = stats[H + h] / (float)N - mean * mean;
    float istd = rsqrtf(var + 1e-5f);
    float sc = gamma[h] * istd;
    ss[h] = sc;
    ss[H + h] = beta[h] - mean * sc;
  }
}

// BN + ReLU, write transposed [H][N] (layers 1,2 feed the next GEMM)
template <int H>
__global__ __launch_bounds__(256) void bn_apply_T(
    const float* __restrict__ X, const float* __restrict__ ss,
    float* __restrict__ Yt, int N) {
  __shared__ float s[64][65];
  int n0 = blockIdx.x * 64;
  int tid = threadIdx.x;
  for (int idx = tid; idx < 64 * (H / 4); idx += 256) {
    int n = idx / (H / 4), c = idx % (H / 4);
    float4 v = make_float4(0.f, 0.f, 0.f, 0.f);
    if (n0 + n < N)
      v = *reinterpret_cast<const float4*>(&X[(size_t)(n0 + n) * H + c * 4]);
    s[n][c * 4 + 0] = v.x; s[n][c * 4 + 1] = v.y;
    s[n][c * 4 + 2] = v.z; s[n][c * 4 + 3] = v.w;
  }
  __syncthreads();
  for (int idx = tid; idx < H * 16; idx += 256) {
    int k = idx >> 4, c = idx & 15;
    int n = c * 4;
    float sc = ss[k], sh = ss[H + k];
    float t0 = s[n + 0][k] * sc + sh;
    float t1 = s[n + 1][k] * sc + sh;
    float t2 = s[n + 2][k] * sc + sh;
    float t3 = s[n + 3][k] * sc + sh;
    float4 v = make_float4(t0 > 0.f ? t0 : 0.f, t1 > 0.f ? t1 : 0.f,
                           t2 > 0.f ? t2 : 0.f, t3 > 0.f ? t3 : 0.f);
    if (n0 + n + 3 < N) {
      *reinterpret_cast<float4*>(&Yt[(size_t)k * N + n0 + n]) = v;
    } else {
      float tv[4] = {v.x, v.y, v.z, v.w};
      for (int j = 0; j < 4; j++)
        if (n0 + n + j < N) Yt[(size_t)k * N + n0 + n + j] = tv[j];
    }
  }
}

// BN + ReLU flat (layer 3, node-major for pooling), H = 16
__global__ __launch_bounds__(256) void bn_apply_flat(
    const float* __restrict__ X, const float* __restrict__ ss,
    float* __restrict__ Y, int total) {
  int i = blockIdx.x * 256 + threadIdx.x;
  if (i < total) {
    int h = i & 15;
    float t = X[i] * ss[h] + ss[16 + h];
    Y[i] = t > 0.f ? t : 0.f;
  }
}

// ---------------- mean-pool + final linear ----------------
__global__ __launch_bounds__(256) void pool_kernel(
    const float* __restrict__ X, const int* __restrict__ batch,
    float* __restrict__ pool, float* __restrict__ cnt, int N) {
  __shared__ float lp[G_ * 16];
  __shared__ float lc[G_];
  int tid = threadIdx.x;
  for (int j = tid; j < G_ * 16; j += 256) lp[j] = 0.f;
  if (tid < G_) lc[tid] = 0.f;
  __syncthreads();
  int tot = N * 16;
  for (int i = blockIdx.x * 256 + tid; i < tot; i += gridDim.x * 256) {
    int n = i >> 4, h = i & 15;
    int g = batch[n];
    atomicAdd(&lp[g * 16 + h], X[i]);
    if (h == 0) atomicAdd(&lc[g], 1.0f);
  }
  __syncthreads();
  for (int j = tid; j < G_ * 16; j += 256) atomicAdd(&pool[j], lp[j]);
  if (tid < G_) atomicAdd(&cnt[tid], lc[tid]);
}

__global__ void final_linear(
    const float* __restrict__ pool, const float* __restrict__ cnt,
    const float* __restrict__ linW, const float* __restrict__ linb,
    float* __restrict__ out) {
  int g = threadIdx.x;
  if (g < G_) {
    float c = fmaxf(cnt[g], 1.0f);
    float acc = 0.f;
    for (int h = 0; h < 16; h++) acc += (pool[g * 16 + h] / c) * linW[h];
    out[g] = acc + linb[0];
  }
}

// ---------------- launch ----------------
extern "C" void kernel_launch(void* const* d_in, const int* in_sizes, int n_in,
                              void* d_out, int out_size, void* d_ws, size_t ws_size,
                              hipStream_t stream) {
  const float* x = (const float*)d_in[0];
  const int* ei = (const int*)d_in[1];
  const int* batch = (const int*)d_in[2];
  const int N = in_sizes[0] / 128;
  const int E = in_sizes[1] / 2;
  const int Etot = E + N;

  char* wsb = (char*)d_ws;
  size_t off = 0;
  auto alloc = [&](size_t bytes) -> void* {
    void* p = wsb + off;
    off += (bytes + 255) & ~(size_t)255;
    return p;
  };
  float* R0 = (float*)alloc((size_t)128 * N * 4);   // x_t / h_t / L3 BN out
  float* R1 = (float*)alloc((size_t)128 * N * 4);   // xlr
  float* R2 = (float*)alloc((size_t)64 * N * 4);    // agg out
  int* deg = (int*)alloc((size_t)N * 4);
  int* row_ptr = (int*)alloc((size_t)(N + 1) * 4);
  int* cursor = (int*)alloc((size_t)N * 4);
  int* bsums = (int*)alloc(4096);
  int* ssrc = (int*)alloc((size_t)Etot * 4);
  float* Wc1 = (float*)alloc(16384 * 4);  float* bc1 = (float*)alloc(128 * 4);
  float* Wc2 = (float*)alloc(4096 * 4);   float* bc2 = (float*)alloc(64 * 4);
  float* Wc3 = (float*)alloc(1024 * 4);   float* bc3 = (float*)alloc(32 * 4);
  float* stats = (float*)alloc(128 * 4);
  float* ss = (float*)alloc(128 * 4);
  float* pool = (float*)alloc((G_ * 16 + G_) * 4);
  float* cnt = pool + G_ * 16;

  const float* Wl1 = (const float*)d_in[3];  const float* bl1 = (const float*)d_in[4];
  const float* Wr1 = (const float*)d_in[5];  const float* br1 = (const float*)d_in[6];
  const float* att1 = (const float*)d_in[7]; const float* bias1 = (const float*)d_in[8];
  const float* g1 = (const float*)d_in[9];   const float* b1 = (const float*)d_in[10];
  const float* Wl2 = (const float*)d_in[11]; const float* bl2 = (const float*)d_in[12];
  const float* Wr2 = (const float*)d_in[13]; const float* br2 = (const float*)d_in[14];
  const float* att2 = (const float*)d_in[15]; const float* bias2 = (const float*)d_in[16];
  const float* g2 = (const float*)d_in[17];  const float* b2 = (const float*)d_in[18];
  const float* Wl3 = (const float*)d_in[19]; const float* bl3 = (const float*)d_in[20];
  const float* Wr3 = (const float*)d_in[21]; const float* br3 = (const float*)d_in[22];
  const float* att3 = (const float*)d_in[23]; const float* bias3 = (const float*)d_in[24];
  const float* g3 = (const float*)d_in[25];  const float* b3 = (const float*)d_in[26];
  const float* linW = (const float*)d_in[27]; const float* linb = (const float*)d_in[28];
  float* out = (float*)d_out;

  int ntiles = (N + 63) / 64;
  int ntiles2 = (N + 127) / 128;
  int nb = (N + 1023) / 1024;
  int nnodeblk = (N + 3) / 4;

  // pack weights
  pack_w<<<64, 256, 0, stream>>>(Wl1, Wr1, bl1, br1, Wc1, bc1, 128, 64);
  pack_w<<<16, 256, 0, stream>>>(Wl2, Wr2, bl2, br2, Wc2, bc2, 64, 32);
  pack_w<<<4, 256, 0, stream>>>(Wl3, Wr3, bl3, br3, Wc3, bc3, 32, 16);

  // transpose x -> R0 [128][N]
  transpose_nf<128><<<dim3(ntiles, 2), 256, 0, stream>>>(x, R0, N);

  // CSR build (XCD-partitioned hist + scatter)
  hipMemsetAsync(deg, 0, (size_t)N * 4, stream);
  edge_hist<<<4096, 256, 0, stream>>>(ei, deg, E, Etot, N);
  scan1<<<nb, 256, 0, stream>>>(deg, row_ptr, bsums, N);
  scan2<<<1, 64, 0, stream>>>(bsums, nb);
  scan3<<<(N + 255) / 256, 256, 0, stream>>>(row_ptr, cursor, bsums, N, Etot);
  scatter_edges<<<4096, 256, 0, stream>>>(ei, cursor, ssrc, E, Etot, N);

  // ---- layer 1 ----
  gemm_fmaj2<128, 128><<<ntiles2, 256, 0, stream>>>(R0, Wc1, bc1, R1, N);
  gat_agg2<64, true><<<nnodeblk, 256, 0, stream>>>(R1, att1, bias1, row_ptr, ssrc, R2, N);
  hipMemsetAsync(stats, 0, 128 * 4, stream);
  bn_stats<64><<<512, 256, 0, stream>>>(R2, stats, N);
  bn_finalize<<<1, 64, 0, stream>>>(stats, g1, b1, ss, 64, N);
  bn_apply_T<64><<<ntiles, 256, 0, stream>>>(R2, ss, R0, N);

  // ---- layer 2 ----
  gemm_fmaj2<64, 64><<<ntiles2, 256, 0, stream>>>(R0, Wc2, bc2, R1, N);
  gat_agg2<32, true><<<nnodeblk, 256, 0, stream>>>(R1, att2, bias2, row_ptr, ssrc, R2, N);
  hipMemsetAsync(stats, 0, 128 * 4, stream);
  bn_stats<32><<<512, 256, 0, stream>>>(R2, stats, N);
  bn_finalize<<<1, 64, 0, stream>>>(stats, g2, b2, ss, 32, N);
  bn_apply_T<32><<<ntiles, 256, 0, stream>>>(R2, ss, R0, N);

  // ---- layer 3 ----
  gemm_fmaj2<32, 32><<<ntiles2, 256, 0, stream>>>(R0, Wc3, bc3, R1, N);
  gat_agg2<16, false><<<nnodeblk, 256, 0, stream>>>(R1, att3, bias3, row_ptr, ssrc, R2, N);
  hipMemsetAsync(stats, 0, 128 * 4, stream);
  bn_stats<16><<<512, 256, 0, stream>>>(R2, stats, N);
  bn_finalize<<<1, 64, 0, stream>>>(stats, g3, b3, ss, 16, N);
  bn_apply_flat<<<(N * 16 + 255) / 256, 256, 0, stream>>>(R2, ss, R0, N * 16);

  // ---- pool + linear ----
  hipMemsetAsync(pool, 0, (G_ * 16 + G_) * 4, stream);
  pool_kernel<<<2048, 256, 0, stream>>>(R0, batch, pool, cnt, N);
  final_linear<<<1, 64, 0, stream>>>(pool, cnt, linW, linb, out);
}

// Round 5
// 579.607 us; speedup vs baseline: 1.4851x; 1.0416x over previous
//
#include <hip/hip_runtime.h>
#include <hip/hip_bf16.h>

// GATv2 x3 + BN + ReLU + mean-pool + linear.
// fp32 math; xlr intermediate stored bf16 (halves the edge-gather traffic).
// N=100000 nodes, E=1.6M edges (+N self loops), F=128, H=64/32/16, G=64.

static constexpr int G_ = 64;

// ---------------- bf16 helpers ----------------
__device__ __forceinline__ float bf2f(unsigned short u) {
  union { unsigned int i; float f; } c;
  c.i = ((unsigned int)u) << 16;
  return c.f;
}
__device__ __forceinline__ unsigned short f2bf(float f) {
  union { float f; unsigned int i; } c;
  c.f = f;
  unsigned int r = c.i + 0x7FFFu + ((c.i >> 16) & 1u);  // round-nearest-even
  return (unsigned short)(r >> 16);
}

// ---------------- weight packing (all 3 layers, one launch) ----------------
__global__ __launch_bounds__(256) void pack_all(
    const float* __restrict__ Wl1, const float* __restrict__ Wr1,
    const float* __restrict__ bl1, const float* __restrict__ br1,
    const float* __restrict__ Wl2, const float* __restrict__ Wr2,
    const float* __restrict__ bl2, const float* __restrict__ br2,
    const float* __restrict__ Wl3, const float* __restrict__ Wr3,
    const float* __restrict__ bl3, const float* __restrict__ br3,
    float* __restrict__ Wc1, float* __restrict__ bc1,
    float* __restrict__ Wc2, float* __restrict__ bc2,
    float* __restrict__ Wc3, float* __restrict__ bc3) {
  int i = blockIdx.x * 256 + threadIdx.x;
  if (i < 128 * 128) { int k = i >> 7, c = i & 127;
    Wc1[i] = (c < 64) ? Wl1[k * 64 + c] : Wr1[k * 64 + c - 64]; }
  if (i < 128) bc1[i] = (i < 64) ? bl1[i] : br1[i - 64];
  if (i < 64 * 64) { int k = i >> 6, c = i & 63;
    Wc2[i] = (c < 32) ? Wl2[k * 32 + c] : Wr2[k * 32 + c - 32]; }
  if (i < 64) bc2[i] = (i < 32) ? bl2[i] : br2[i - 32];
  if (i < 32 * 32) { int k = i >> 5, c = i & 31;
    Wc3[i] = (c < 16) ? Wl3[k * 16 + c] : Wr3[k * 16 + c - 16]; }
  if (i < 32) bc3[i] = (i < 16) ? bl3[i] : br3[i - 16];
}

// ---------------- transpose [N][FI] -> [FI][N] ----------------
template <int FI>
__global__ __launch_bounds__(256) void transpose_nf(
    const float* __restrict__ A, float* __restrict__ At, int N) {
  __shared__ float s[64][65];
  int n0 = blockIdx.x * 64, k0 = blockIdx.y * 64;
  int tid = threadIdx.x;
  for (int idx = tid; idx < 64 * 16; idx += 256) {
    int n = idx >> 4, c = idx & 15;
    float4 v = make_float4(0.f, 0.f, 0.f, 0.f);
    if (n0 + n < N)
      v = *reinterpret_cast<const float4*>(&A[(size_t)(n0 + n) * FI + k0 + c * 4]);
    s[n][c * 4 + 0] = v.x; s[n][c * 4 + 1] = v.y;
    s[n][c * 4 + 2] = v.z; s[n][c * 4 + 3] = v.w;
  }
  __syncthreads();
  for (int idx = tid; idx < 64 * 16; idx += 256) {
    int k = idx >> 4, c = idx & 15;
    int n = c * 4;
    if (n0 + n + 3 < N) {
      float4 v = make_float4(s[n][k], s[n + 1][k], s[n + 2][k], s[n + 3][k]);
      *reinterpret_cast<float4*>(&At[(size_t)(k0 + k) * N + n0 + n]) = v;
    } else {
      for (int j = 0; j < 4; j++)
        if (n0 + n + j < N) At[(size_t)(k0 + k) * N + n0 + n + j] = s[n + j][k];
    }
  }
}

// ---------------- CSR build (XCD-partitioned by dst range) ----------------
__global__ __launch_bounds__(256) void edge_hist(
    const int* __restrict__ ei, int* __restrict__ deg, int E, int Etot, int N) {
  int p = blockIdx.x & 7;
  int q = blockIdx.x >> 3;
  int nbq = gridDim.x >> 3;
  float scale = 8.0f / (float)N;
  for (int i = q * 256 + threadIdx.x; i < Etot; i += nbq * 256) {
    int dst = (i < E) ? ei[E + i] : (i - E);
    int pp = min((int)((float)dst * scale), 7);
    if (pp == p) atomicAdd(&deg[dst], 1);
  }
}

__global__ __launch_bounds__(256) void scan1(
    const int* __restrict__ deg, int* __restrict__ part, int* __restrict__ bsums, int n) {
  __shared__ int ts[256];
  int t = threadIdx.x, b = blockIdx.x;
  int base = b * 1024 + t * 4;
  int d[4];
#pragma unroll
  for (int q = 0; q < 4; q++) d[q] = (base + q < n) ? deg[base + q] : 0;
  int s = d[0] + d[1] + d[2] + d[3];
  ts[t] = s;
  __syncthreads();
  for (int o = 1; o < 256; o <<= 1) {
    int v = (t >= o) ? ts[t - o] : 0;
    __syncthreads();
    ts[t] += v;
    __syncthreads();
  }
  int incl = ts[t];
  if (t == 255) bsums[b] = incl;
  int run = incl - s;
#pragma unroll
  for (int q = 0; q < 4; q++) {
    if (base + q < n) part[base + q] = run;
    run += d[q];
  }
}

// block-parallel scan of bsums (nb <= 256)
__global__ void scan2(int* bsums, int nb) {
  __shared__ int s[256];
  int t = threadIdx.x;
  int v = (t < nb) ? bsums[t] : 0;
  s[t] = v;
  __syncthreads();
  for (int o = 1; o < 256; o <<= 1) {
    int u = (t >= o) ? s[t - o] : 0;
    __syncthreads();
    s[t] += u;
    __syncthreads();
  }
  if (t < nb) bsums[t] = s[t] - v;  // exclusive
}

__global__ __launch_bounds__(256) void scan3(
    int* __restrict__ rp, int* __restrict__ cur, const int* __restrict__ bsums,
    int n, int Etot) {
  int i = blockIdx.x * 256 + threadIdx.x;
  if (i < n) {
    int v = rp[i] + bsums[i >> 10];
    rp[i] = v; cur[i] = v;
  }
  if (i == 0) rp[n] = Etot;
}

__global__ __launch_bounds__(256) void scatter_edges(
    const int* __restrict__ ei, int* __restrict__ cur, int* __restrict__ ssrc,
    int E, int Etot, int N) {
  int p = blockIdx.x & 7;
  int q = blockIdx.x >> 3;
  int nbq = gridDim.x >> 3;
  float scale = 8.0f / (float)N;
  for (int i = q * 256 + threadIdx.x; i < Etot; i += nbq * 256) {
    int dst = (i < E) ? ei[E + i] : (i - E);
    int pp = min((int)((float)dst * scale), 7);
    if (pp != p) continue;
    int src = (i < E) ? ei[i] : (i - E);
    int pos = atomicAdd(&cur[dst], 1);
    ssrc[pos] = src;
  }
}

// ---------------- GEMM: Cb16[N][FO] = At^T[N][FI] @ Wcat[FI][FO] + bcat ----
// 128-node x FO block tile, 8 x FO/16 register tile, KC=32 chunks; bf16 out.
template <int FI, int FO>
__global__ __launch_bounds__(256) void gemm_fmaj2(
    const float* __restrict__ At, const float* __restrict__ Wcat,
    const float* __restrict__ bcat, unsigned short* __restrict__ Cb, int N) {
  constexpr int KC = 32;
  constexpr int CT = FO / 16;  // cols per thread: 8 / 4 / 2
  __shared__ float As[KC * 128];
  __shared__ float Ws[KC * FO];
  int tid = threadIdx.x;
  int ng = tid & 15;
  int hg = tid >> 4;
  int n0 = blockIdx.x * 128;
  bool full = (n0 + 128 <= N);

  float acc[8][CT];
#pragma unroll
  for (int i = 0; i < 8; i++)
#pragma unroll
    for (int j = 0; j < CT; j++) acc[i][j] = 0.f;

  for (int kc = 0; kc < FI; kc += KC) {
    __syncthreads();
    {
      int r = tid >> 5;
      int c = (tid & 31) * 4;
      for (int rr = r; rr < KC; rr += 8) {
        float4 v;
        if (full) {
          v = *reinterpret_cast<const float4*>(&At[(size_t)(kc + rr) * N + n0 + c]);
        } else {
          float tmp[4];
#pragma unroll
          for (int j = 0; j < 4; j++)
            tmp[j] = (n0 + c + j < N) ? At[(size_t)(kc + rr) * N + n0 + c + j] : 0.f;
          v = make_float4(tmp[0], tmp[1], tmp[2], tmp[3]);
        }
        *reinterpret_cast<float4*>(&As[rr * 128 + c]) = v;
      }
    }
    for (int idx = tid; idx < KC * FO / 4; idx += 256)
      *reinterpret_cast<float4*>(&Ws[idx * 4]) =
          *reinterpret_cast<const float4*>(&Wcat[kc * FO + idx * 4]);
    __syncthreads();
#pragma unroll
    for (int kk = 0; kk < KC; kk++) {
      float4 alo = *reinterpret_cast<float4*>(&As[kk * 128 + 4 * ng]);
      float4 ahi = *reinterpret_cast<float4*>(&As[kk * 128 + 64 + 4 * ng]);
      float a[8] = {alo.x, alo.y, alo.z, alo.w, ahi.x, ahi.y, ahi.z, ahi.w};
      float w[CT];
#pragma unroll
      for (int j = 0; j < CT; j++) w[j] = Ws[kk * FO + hg * CT + j];
#pragma unroll
      for (int i = 0; i < 8; i++)
#pragma unroll
        for (int j = 0; j < CT; j++) acc[i][j] = fmaf(a[i], w[j], acc[i][j]);
    }
  }

  float b[CT];
#pragma unroll
  for (int j = 0; j < CT; j++) b[j] = bcat[hg * CT + j];
#pragma unroll
  for (int i = 0; i < 8; i++) {
    int n = n0 + ((i < 4) ? (4 * ng + i) : (64 + 4 * ng + (i - 4)));
    if (n < N) {
      unsigned int u[CT / 2];
#pragma unroll
      for (int j2 = 0; j2 < CT / 2; j2++) {
        unsigned int lo = f2bf(acc[i][2 * j2] + b[2 * j2]);
        unsigned int hi = f2bf(acc[i][2 * j2 + 1] + b[2 * j2 + 1]);
        u[j2] = lo | (hi << 16);
      }
      unsigned short* dst = &Cb[(size_t)n * FO + hg * CT];
      if constexpr (CT == 8) {
        *reinterpret_cast<uint4*>(dst) = make_uint4(u[0], u[1], u[2], u[3]);
      } else if constexpr (CT == 4) {
        *reinterpret_cast<uint2*>(dst) = make_uint2(u[0], u[1]);
      } else {
        *reinterpret_cast<unsigned int*>(dst) = u[0];
      }
    }
  }
}

// ---------------- GATv2 aggregation: bf16 gather, defer-max softmax -------
__device__ __forceinline__ float lrelu02(float z) {
  return (z > 0.f) ? z : 0.2f * z;
}

template <int H, bool UN2>
__global__ __launch_bounds__(256) void gat_agg2(
    const unsigned short* __restrict__ xlr, const float* __restrict__ att,
    const float* __restrict__ bias, const int* __restrict__ rp,
    const int* __restrict__ ssrc, float* __restrict__ out, int N) {
  constexpr int L = H / 4;    // lanes per edge
  constexpr int C = 64 / L;   // concurrent edges per wave
  int v = blockIdx.x * 4 + (threadIdx.x >> 6);
  if (v >= N) return;
  int lane = threadIdx.x & 63;
  int fl = lane % L;
  int sub = lane / L;

  ushort4 qr = *reinterpret_cast<const ushort4*>(&xlr[(size_t)v * (2 * H) + H + fl * 4]);
  float xr0 = bf2f(qr.x), xr1 = bf2f(qr.y), xr2 = bf2f(qr.z), xr3 = bf2f(qr.w);
  const float4 a4 = *reinterpret_cast<const float4*>(&att[fl * 4]);
  int beg = rp[v], end = rp[v + 1];

  float mA = -3.0e38f, dA = 0.f;
  float4 accA = make_float4(0.f, 0.f, 0.f, 0.f);
  float mB = -3.0e38f, dB = 0.f;
  float4 accB = make_float4(0.f, 0.f, 0.f, 0.f);

  constexpr int STEP = UN2 ? 2 * C : C;

  for (int j = beg + sub; j < end; j += STEP) {
    {
      int u = ssrc[j];
      ushort4 q = *reinterpret_cast<const ushort4*>(&xlr[(size_t)u * (2 * H) + fl * 4]);
      float x0 = bf2f(q.x), x1 = bf2f(q.y), x2 = bf2f(q.z), x3 = bf2f(q.w);
      float t = a4.x * lrelu02(x0 + xr0);
      t = fmaf(a4.y, lrelu02(x1 + xr1), t);
      t = fmaf(a4.z, lrelu02(x2 + xr2), t);
      t = fmaf(a4.w, lrelu02(x3 + xr3), t);
#pragma unroll
      for (int o = L / 2; o >= 1; o >>= 1) t += __shfl_xor(t, o);
      float diff = t - mA;
      if (diff > 8.f) {
        float sc = __expf(-diff);
        dA *= sc;
        accA.x *= sc; accA.y *= sc; accA.z *= sc; accA.w *= sc;
        mA = t; diff = 0.f;
      }
      float w = __expf(diff);
      dA += w;
      accA.x = fmaf(w, x0, accA.x);
      accA.y = fmaf(w, x1, accA.y);
      accA.z = fmaf(w, x2, accA.z);
      accA.w = fmaf(w, x3, accA.w);
    }
    if (UN2) {
      int j2 = j + C;
      if (j2 < end) {
        int u = ssrc[j2];
        ushort4 q = *reinterpret_cast<const ushort4*>(&xlr[(size_t)u * (2 * H) + fl * 4]);
        float x0 = bf2f(q.x), x1 = bf2f(q.y), x2 = bf2f(q.z), x3 = bf2f(q.w);
        float t = a4.x * lrelu02(x0 + xr0);
        t = fmaf(a4.y, lrelu02(x1 + xr1), t);
        t = fmaf(a4.z, lrelu02(x2 + xr2), t);
        t = fmaf(a4.w, lrelu02(x3 + xr3), t);
#pragma unroll
        for (int o = L / 2; o >= 1; o >>= 1) t += __shfl_xor(t, o);
        float diff = t - mB;
        if (diff > 8.f) {
          float sc = __expf(-diff);
          dB *= sc;
          accB.x *= sc; accB.y *= sc; accB.z *= sc; accB.w *= sc;
          mB = t; diff = 0.f;
        }
        float w = __expf(diff);
        dB += w;
        accB.x = fmaf(w, x0, accB.x);
        accB.y = fmaf(w, x1, accB.y);
        accB.z = fmaf(w, x2, accB.z);
        accB.w = fmaf(w, x3, accB.w);
      }
    }
  }

  if (UN2) {
    float mn = fmaxf(mA, mB);
    float s1 = __expf(mA - mn), s2 = __expf(mB - mn);
    dA = dA * s1 + dB * s2;
    accA.x = accA.x * s1 + accB.x * s2;
    accA.y = accA.y * s1 + accB.y * s2;
    accA.z = accA.z * s1 + accB.z * s2;
    accA.w = accA.w * s1 + accB.w * s2;
    mA = mn;
  }

#pragma unroll
  for (int o = L; o < 64; o <<= 1) {
    float mo = __shfl_xor(mA, o);
    float d2 = __shfl_xor(dA, o);
    float ax = __shfl_xor(accA.x, o);
    float ay = __shfl_xor(accA.y, o);
    float az = __shfl_xor(accA.z, o);
    float aw = __shfl_xor(accA.w, o);
    float mn = fmaxf(mA, mo);
    float s1 = __expf(mA - mn), s2 = __expf(mo - mn);
    dA = dA * s1 + d2 * s2;
    accA.x = accA.x * s1 + ax * s2;
    accA.y = accA.y * s1 + ay * s2;
    accA.z = accA.z * s1 + az * s2;
    accA.w = accA.w * s1 + aw * s2;
    mA = mn;
  }

  if (lane < L) {
    float inv = 1.f / (dA + 1e-16f);
    const float4 b4 = *reinterpret_cast<const float4*>(&bias[fl * 4]);
    float4 o4 = make_float4(fmaf(accA.x, inv, b4.x), fmaf(accA.y, inv, b4.y),
                            fmaf(accA.z, inv, b4.z), fmaf(accA.w, inv, b4.w));
    *reinterpret_cast<float4*>(&out[(size_t)v * H + fl * 4]) = o4;
  }
}

// ---------------- BatchNorm ----------------
template <int H>
__global__ __launch_bounds__(256) void bn_stats(
    const float* __restrict__ X, float* __restrict__ stats, int N) {
  __shared__ float ls[256], ls2[256];
  int tid = threadIdx.x;
  int h = tid % H;
  constexpr int RPB = 256 / H;
  int r0 = blockIdx.x * RPB + tid / H;
  float s = 0.f, s2 = 0.f;
  for (int n = r0; n < N; n += gridDim.x * RPB) {
    float val = X[(size_t)n * H + h];
    s += val; s2 += val * val;
  }
  ls[tid] = s; ls2[tid] = s2;
  __syncthreads();
  if (tid < H) {
    for (int g = 1; g < RPB; g++) { s += ls[tid + g * H]; s2 += ls2[tid + g * H]; }
    atomicAdd(&stats[h], s);
    atomicAdd(&stats[H + h], s2);
  }
}

__global__ void bn_finalize(
    const float* __restrict__ stats, const float* __restrict__ gamma,
    const float* __restrict__ beta, float* __restrict__ ss, int H, int N) {
  int h = threadIdx.x;
  if (h < H) {
    float mean = stats[h] / (float)N;
    float var = stats[H + h] / (float)N - mean * mean;
    float istd = rsqrtf(var + 1e-5f);
    float sc = gamma[h] * istd;
    ss[h] = sc;
    ss[H + h] = beta[h] - mean * sc;
  }
}

// BN + ReLU, write transposed [H][N] (layers 1,2 feed the next GEMM)
template <int H>
__global__ __launch_bounds__(256) void bn_apply_T(
    const float* __restrict__ X, const float* __restrict__ ss,
    float* __restrict__ Yt, int N) {
  __shared__ float s[64][65];
  int n0 = blockIdx.x * 64;
  int tid = threadIdx.x;
  for (int idx = tid; idx < 64 * (H / 4); idx += 256) {
    int n = idx / (H / 4), c = idx % (H / 4);
    float4 v = make_float4(0.f, 0.f, 0.f, 0.f);
    if (n0 + n < N)
      v = *reinterpret_cast<const float4*>(&X[(size_t)(n0 + n) * H + c * 4]);
    s[n][c * 4 + 0] = v.x; s[n][c * 4 + 1] = v.y;
    s[n][c * 4 + 2] = v.z; s[n][c * 4 + 3] = v.w;
  }
  __syncthreads();
  for (int idx = tid; idx < H * 16; idx += 256) {
    int k = idx >> 4, c = idx & 15;
    int n = c * 4;
    float sc = ss[k], sh = ss[H + k];
    float t0 = s[n + 0][k] * sc + sh;
    float t1 = s[n + 1][k] * sc + sh;
    float t2 = s[n + 2][k] * sc + sh;
    float t3 = s[n + 3][k] * sc + sh;
    float4 v = make_float4(t0 > 0.f ? t0 : 0.f, t1 > 0.f ? t1 : 0.f,
                           t2 > 0.f ? t2 : 0.f, t3 > 0.f ? t3 : 0.f);
    if (n0 + n + 3 < N) {
      *reinterpret_cast<float4*>(&Yt[(size_t)k * N + n0 + n]) = v;
    } else {
      float tv[4] = {v.x, v.y, v.z, v.w};
      for (int j = 0; j < 4; j++)
        if (n0 + n + j < N) Yt[(size_t)k * N + n0 + n + j] = tv[j];
    }
  }
}

// ---------------- fused BN+ReLU + mean-pool, then final linear ------------
__global__ __launch_bounds__(256) void pool_kernel(
    const float* __restrict__ X, const float* __restrict__ ss,
    const int* __restrict__ batch, float* __restrict__ pool,
    float* __restrict__ cnt, int N) {
  __shared__ float lp[G_ * 16];
  __shared__ float lc[G_];
  int tid = threadIdx.x;
  for (int j = tid; j < G_ * 16; j += 256) lp[j] = 0.f;
  if (tid < G_) lc[tid] = 0.f;
  __syncthreads();
  int tot = N * 16;
  for (int i = blockIdx.x * 256 + tid; i < tot; i += gridDim.x * 256) {
    int n = i >> 4, h = i & 15;
    int g = batch[n];
    float t = X[i] * ss[h] + ss[16 + h];
    t = (t > 0.f) ? t : 0.f;
    atomicAdd(&lp[g * 16 + h], t);
    if (h == 0) atomicAdd(&lc[g], 1.0f);
  }
  __syncthreads();
  for (int j = tid; j < G_ * 16; j += 256) atomicAdd(&pool[j], lp[j]);
  if (tid < G_) atomicAdd(&cnt[tid], lc[tid]);
}

__global__ void final_linear(
    const float* __restrict__ pool, const float* __restrict__ cnt,
    const float* __restrict__ linW, const float* __restrict__ linb,
    float* __restrict__ out) {
  int g = threadIdx.x;
  if (g < G_) {
    float c = fmaxf(cnt[g], 1.0f);
    float acc = 0.f;
    for (int h = 0; h < 16; h++) acc += (pool[g * 16 + h] / c) * linW[h];
    out[g] = acc + linb[0];
  }
}

// ---------------- launch ----------------
extern "C" void kernel_launch(void* const* d_in, const int* in_sizes, int n_in,
                              void* d_out, int out_size, void* d_ws, size_t ws_size,
                              hipStream_t stream) {
  const float* x = (const float*)d_in[0];
  const int* ei = (const int*)d_in[1];
  const int* batch = (const int*)d_in[2];
  const int N = in_sizes[0] / 128;
  const int E = in_sizes[1] / 2;
  const int Etot = E + N;

  char* wsb = (char*)d_ws;
  size_t off = 0;
  auto alloc = [&](size_t bytes) -> void* {
    void* p = wsb + off;
    off += (bytes + 255) & ~(size_t)255;
    return p;
  };
  float* R0 = (float*)alloc((size_t)128 * N * 4);          // x_t / h_t (feature-major, fp32)
  unsigned short* R1b = (unsigned short*)alloc((size_t)128 * N * 2);  // xlr (bf16)
  float* R2 = (float*)alloc((size_t)64 * N * 4);           // agg out (fp32)
  int* row_ptr = (int*)alloc((size_t)(N + 1) * 4);
  int* cursor = (int*)alloc((size_t)N * 4);
  int* bsums = (int*)alloc(4096);
  int* ssrc = (int*)alloc((size_t)Etot * 4);
  float* Wc1 = (float*)alloc(16384 * 4);  float* bc1 = (float*)alloc(128 * 4);
  float* Wc2 = (float*)alloc(4096 * 4);   float* bc2 = (float*)alloc(64 * 4);
  float* Wc3 = (float*)alloc(1024 * 4);   float* bc3 = (float*)alloc(32 * 4);
  float* ss = (float*)alloc(128 * 4);
  // single zeroed region: deg[N] | stats1[128] | stats2[128] | stats3[128] | pool[1024] | cnt[64]
  size_t zelems = (size_t)N + 3 * 128 + G_ * 16 + G_;
  char* zb = (char*)alloc(zelems * 4);
  int* deg = (int*)zb;
  float* stats1 = (float*)(zb + (size_t)N * 4);
  float* stats2 = stats1 + 128;
  float* stats3 = stats2 + 128;
  float* pool = stats3 + 128;
  float* cnt = pool + G_ * 16;

  const float* Wl1 = (const float*)d_in[3];  const float* bl1 = (const float*)d_in[4];
  const float* Wr1 = (const float*)d_in[5];  const float* br1 = (const float*)d_in[6];
  const float* att1 = (const float*)d_in[7]; const float* bias1 = (const float*)d_in[8];
  const float* g1 = (const float*)d_in[9];   const float* b1 = (const float*)d_in[10];
  const float* Wl2 = (const float*)d_in[11]; const float* bl2 = (const float*)d_in[12];
  const float* Wr2 = (const float*)d_in[13]; const float* br2 = (const float*)d_in[14];
  const float* att2 = (const float*)d_in[15]; const float* bias2 = (const float*)d_in[16];
  const float* g2 = (const float*)d_in[17];  const float* b2 = (const float*)d_in[18];
  const float* Wl3 = (const float*)d_in[19]; const float* bl3 = (const float*)d_in[20];
  const float* Wr3 = (const float*)d_in[21]; const float* br3 = (const float*)d_in[22];
  const float* att3 = (const float*)d_in[23]; const float* bias3 = (const float*)d_in[24];
  const float* g3 = (const float*)d_in[25];  const float* b3 = (const float*)d_in[26];
  const float* linW = (const float*)d_in[27]; const float* linb = (const float*)d_in[28];
  float* out = (float*)d_out;

  int ntiles = (N + 63) / 64;
  int ntiles2 = (N + 127) / 128;
  int nb = (N + 1023) / 1024;
  int nnodeblk = (N + 3) / 4;

  // weights + zero scratch + input transpose
  pack_all<<<64, 256, 0, stream>>>(Wl1, Wr1, bl1, br1, Wl2, Wr2, bl2, br2,
                                   Wl3, Wr3, bl3, br3, Wc1, bc1, Wc2, bc2, Wc3, bc3);
  hipMemsetAsync(zb, 0, zelems * 4, stream);
  transpose_nf<128><<<dim3(ntiles, 2), 256, 0, stream>>>(x, R0, N);

  // CSR build (XCD-partitioned hist + scatter)
  edge_hist<<<4096, 256, 0, stream>>>(ei, deg, E, Etot, N);
  scan1<<<nb, 256, 0, stream>>>(deg, row_ptr, bsums, N);
  scan2<<<1, 256, 0, stream>>>(bsums, nb);
  scan3<<<(N + 255) / 256, 256, 0, stream>>>(row_ptr, cursor, bsums, N, Etot);
  scatter_edges<<<4096, 256, 0, stream>>>(ei, cursor, ssrc, E, Etot, N);

  // ---- layer 1 ----
  gemm_fmaj2<128, 128><<<ntiles2, 256, 0, stream>>>(R0, Wc1, bc1, R1b, N);
  gat_agg2<64, true><<<nnodeblk, 256, 0, stream>>>(R1b, att1, bias1, row_ptr, ssrc, R2, N);
  bn_stats<64><<<512, 256, 0, stream>>>(R2, stats1, N);
  bn_finalize<<<1, 64, 0, stream>>>(stats1, g1, b1, ss, 64, N);
  bn_apply_T<64><<<ntiles, 256, 0, stream>>>(R2, ss, R0, N);

  // ---- layer 2 ----
  gemm_fmaj2<64, 64><<<ntiles2, 256, 0, stream>>>(R0, Wc2, bc2, R1b, N);
  gat_agg2<32, true><<<nnodeblk, 256, 0, stream>>>(R1b, att2, bias2, row_ptr, ssrc, R2, N);
  bn_stats<32><<<512, 256, 0, stream>>>(R2, stats2, N);
  bn_finalize<<<1, 64, 0, stream>>>(stats2, g2, b2, ss, 32, N);
  bn_apply_T<32><<<ntiles, 256, 0, stream>>>(R2, ss, R0, N);

  // ---- layer 3 ----
  gemm_fmaj2<32, 32><<<ntiles2, 256, 0, stream>>>(R0, Wc3, bc3, R1b, N);
  gat_agg2<16, false><<<nnodeblk, 256, 0, stream>>>(R1b, att3, bias3, row_ptr, ssrc, R2, N);
  bn_stats<16><<<512, 256, 0, stream>>>(R2, stats3, N);
  bn_finalize<<<1, 64, 0, stream>>>(stats3, g3, b3, ss, 16, N);

  // ---- fused BN+ReLU+pool + linear ----
  pool_kernel<<<2048, 256, 0, stream>>>(R2, ss, batch, pool, cnt, N);
  final_linear<<<1, 64, 0, stream>>>(pool, cnt, linW, linb, out);
}

// Round 6
// 518.399 us; speedup vs baseline: 1.6604x; 1.1181x over previous
//
#include <hip/hip_runtime.h>
#include <hip/hip_bf16.h>

// GATv2 x3 + BN + ReLU + mean-pool + linear.
// MFMA bf16 GEMMs (no LDS), fp32 edge-softmax math, bf16 xlr gathers.
// N=100000 nodes, E=1.6M edges (+N self loops), F=128, H=64/32/16, G=64.

static constexpr int G_ = 64;

typedef short bfrag __attribute__((ext_vector_type(8)));   // 8 bf16 = 4 VGPR
typedef float facc  __attribute__((ext_vector_type(4)));   // 4 f32 acc

// ---------------- bf16 helpers ----------------
__device__ __forceinline__ float bf2f(unsigned short u) {
  union { unsigned int i; float f; } c;
  c.i = ((unsigned int)u) << 16;
  return c.f;
}
__device__ __forceinline__ unsigned short f2bf(float f) {
  union { float f; unsigned int i; } c;
  c.f = f;
  unsigned int r = c.i + 0x7FFFu + ((c.i >> 16) & 1u);  // round-nearest-even
  return (unsigned short)(r >> 16);
}

// ---------------- weight packing: Wt[col][k] bf16 (B^T fragment layout) ----
__global__ __launch_bounds__(256) void pack_all(
    const float* __restrict__ Wl1, const float* __restrict__ Wr1,
    const float* __restrict__ bl1, const float* __restrict__ br1,
    const float* __restrict__ Wl2, const float* __restrict__ Wr2,
    const float* __restrict__ bl2, const float* __restrict__ br2,
    const float* __restrict__ Wl3, const float* __restrict__ Wr3,
    const float* __restrict__ bl3, const float* __restrict__ br3,
    unsigned short* __restrict__ Wt1, float* __restrict__ bc1,
    unsigned short* __restrict__ Wt2, float* __restrict__ bc2,
    unsigned short* __restrict__ Wt3, float* __restrict__ bc3) {
  int i = blockIdx.x * 256 + threadIdx.x;
  if (i < 128 * 128) { int c = i >> 7, k = i & 127;
    Wt1[i] = f2bf((c < 64) ? Wl1[k * 64 + c] : Wr1[k * 64 + (c - 64)]); }
  if (i < 128) bc1[i] = (i < 64) ? bl1[i] : br1[i - 64];
  if (i < 64 * 64) { int c = i >> 6, k = i & 63;
    Wt2[i] = f2bf((c < 32) ? Wl2[k * 32 + c] : Wr2[k * 32 + (c - 32)]); }
  if (i < 64) bc2[i] = (i < 32) ? bl2[i] : br2[i - 32];
  if (i < 32 * 32) { int c = i >> 5, k = i & 31;
    Wt3[i] = f2bf((c < 16) ? Wl3[k * 16 + c] : Wr3[k * 16 + (c - 16)]); }
  if (i < 32) bc3[i] = (i < 16) ? bl3[i] : br3[i - 16];
}

// ---------------- CSR build (XCD-partitioned by dst range) ----------------
__global__ __launch_bounds__(256) void edge_hist(
    const int* __restrict__ ei, int* __restrict__ deg, int E, int Etot, int N) {
  int p = blockIdx.x & 7;
  int q = blockIdx.x >> 3;
  int nbq = gridDim.x >> 3;
  float scale = 8.0f / (float)N;
  for (int i = q * 256 + threadIdx.x; i < Etot; i += nbq * 256) {
    int dst = (i < E) ? ei[E + i] : (i - E);
    int pp = min((int)((float)dst * scale), 7);
    if (pp == p) atomicAdd(&deg[dst], 1);
  }
}

__global__ __launch_bounds__(256) void scan1(
    const int* __restrict__ deg, int* __restrict__ part, int* __restrict__ bsums, int n) {
  __shared__ int ts[256];
  int t = threadIdx.x, b = blockIdx.x;
  int base = b * 1024 + t * 4;
  int d[4];
#pragma unroll
  for (int q = 0; q < 4; q++) d[q] = (base + q < n) ? deg[base + q] : 0;
  int s = d[0] + d[1] + d[2] + d[3];
  ts[t] = s;
  __syncthreads();
  for (int o = 1; o < 256; o <<= 1) {
    int v = (t >= o) ? ts[t - o] : 0;
    __syncthreads();
    ts[t] += v;
    __syncthreads();
  }
  int incl = ts[t];
  if (t == 255) bsums[b] = incl;
  int run = incl - s;
#pragma unroll
  for (int q = 0; q < 4; q++) {
    if (base + q < n) part[base + q] = run;
    run += d[q];
  }
}

__global__ void scan2(int* bsums, int nb) {
  __shared__ int s[256];
  int t = threadIdx.x;
  int v = (t < nb) ? bsums[t] : 0;
  s[t] = v;
  __syncthreads();
  for (int o = 1; o < 256; o <<= 1) {
    int u = (t >= o) ? s[t - o] : 0;
    __syncthreads();
    s[t] += u;
    __syncthreads();
  }
  if (t < nb) bsums[t] = s[t] - v;  // exclusive
}

__global__ __launch_bounds__(256) void scan3(
    int* __restrict__ rp, int* __restrict__ cur, const int* __restrict__ bsums,
    int n, int Etot) {
  int i = blockIdx.x * 256 + threadIdx.x;
  if (i < n) {
    int v = rp[i] + bsums[i >> 10];
    rp[i] = v; cur[i] = v;
  }
  if (i == 0) rp[n] = Etot;
}

__global__ __launch_bounds__(256) void scatter_edges(
    const int* __restrict__ ei, int* __restrict__ cur, int* __restrict__ ssrc,
    int E, int Etot, int N) {
  int p = blockIdx.x & 7;
  int q = blockIdx.x >> 3;
  int nbq = gridDim.x >> 3;
  float scale = 8.0f / (float)N;
  for (int i = q * 256 + threadIdx.x; i < Etot; i += nbq * 256) {
    int dst = (i < E) ? ei[E + i] : (i - E);
    int pp = min((int)((float)dst * scale), 7);
    if (pp != p) continue;
    int src = (i < E) ? ei[i] : (i - E);
    int pos = atomicAdd(&cur[dst], 1);
    ssrc[pos] = src;
  }
}

// ---------------- MFMA GEMM: Cb16[N][FO] = A[N][FI] @ Wt^T + bcat ---------
// Block = 64 nodes, 4 waves; wave w owns M-tile w (16 nodes) x all FO/16
// N-tiles. Fragments direct from global (no LDS). 16x16x32 bf16 MFMA:
// A[m][k]: m=lane&15, k=(lane>>4)*8+e (8 contiguous bf16 per lane — the
// m92-verified layout); Wt[col][k] is the matching B^T load; C/D: col=lane&15,
// row=(lane>>4)*4+reg (m89-verified).
template <int FI, int FO, bool AFP32>
__global__ __launch_bounds__(256) void gemm_mfma(
    const void* __restrict__ Ain, const unsigned short* __restrict__ Wt,
    const float* __restrict__ bcat, unsigned short* __restrict__ Cb, int N) {
  constexpr int NT = FO / 16;
  constexpr int KS = FI / 32;
  int tid = threadIdx.x;
  int w = tid >> 6;
  int lr = tid & 15;
  int lg = (tid & 63) >> 4;
  int n0 = blockIdx.x * 64;
  int arow = min(n0 + w * 16 + lr, N - 1);  // clamp: no OOB, stores masked

  facc acc[NT];
#pragma unroll
  for (int t = 0; t < NT; t++)
#pragma unroll
    for (int e = 0; e < 4; e++) acc[t][e] = 0.f;

#pragma unroll
  for (int ks = 0; ks < KS; ks++) {
    int k0 = ks * 32 + lg * 8;
    bfrag a;
    if constexpr (AFP32) {
      const float* Af = (const float*)Ain;
      const float* p = &Af[(size_t)arow * FI + k0];
      float4 lo = *reinterpret_cast<const float4*>(p);
      float4 hi = *reinterpret_cast<const float4*>(p + 4);
      union { bfrag v; unsigned short u[8]; } cv;
      cv.u[0] = f2bf(lo.x); cv.u[1] = f2bf(lo.y);
      cv.u[2] = f2bf(lo.z); cv.u[3] = f2bf(lo.w);
      cv.u[4] = f2bf(hi.x); cv.u[5] = f2bf(hi.y);
      cv.u[6] = f2bf(hi.z); cv.u[7] = f2bf(hi.w);
      a = cv.v;
    } else {
      const unsigned short* Ab = (const unsigned short*)Ain;
      a = *reinterpret_cast<const bfrag*>(&Ab[(size_t)arow * FI + k0]);
    }
#pragma unroll
    for (int t = 0; t < NT; t++) {
      bfrag b = *reinterpret_cast<const bfrag*>(&Wt[(size_t)(t * 16 + lr) * FI + k0]);
      acc[t] = __builtin_amdgcn_mfma_f32_16x16x32_bf16(a, b, acc[t], 0, 0, 0);
    }
  }

#pragma unroll
  for (int t = 0; t < NT; t++) {
    int col = t * 16 + lr;
    float bias = bcat[col];
#pragma unroll
    for (int r = 0; r < 4; r++) {
      int n = n0 + w * 16 + lg * 4 + r;
      if (n < N) Cb[(size_t)n * FO + col] = f2bf(acc[t][r] + bias);
    }
  }
}

// ---------------- GATv2 aggregation: bf16 gather, defer-max softmax -------
__device__ __forceinline__ float lrelu02(float z) {
  return (z > 0.f) ? z : 0.2f * z;
}

template <int H, bool UN2>
__global__ __launch_bounds__(256) void gat_agg2(
    const unsigned short* __restrict__ xlr, const float* __restrict__ att,
    const float* __restrict__ bias, const int* __restrict__ rp,
    const int* __restrict__ ssrc, float* __restrict__ out, int N) {
  constexpr int L = H / 4;    // lanes per edge
  constexpr int C = 64 / L;   // concurrent edges per wave
  int v = blockIdx.x * 4 + (threadIdx.x >> 6);
  if (v >= N) return;
  int lane = threadIdx.x & 63;
  int fl = lane % L;
  int sub = lane / L;

  ushort4 qr = *reinterpret_cast<const ushort4*>(&xlr[(size_t)v * (2 * H) + H + fl * 4]);
  float xr0 = bf2f(qr.x), xr1 = bf2f(qr.y), xr2 = bf2f(qr.z), xr3 = bf2f(qr.w);
  const float4 a4 = *reinterpret_cast<const float4*>(&att[fl * 4]);
  int beg = rp[v], end = rp[v + 1];

  float mA = -3.0e38f, dA = 0.f;
  float4 accA = make_float4(0.f, 0.f, 0.f, 0.f);
  float mB = -3.0e38f, dB = 0.f;
  float4 accB = make_float4(0.f, 0.f, 0.f, 0.f);

  constexpr int STEP = UN2 ? 2 * C : C;

  for (int j = beg + sub; j < end; j += STEP) {
    {
      int u = ssrc[j];
      ushort4 q = *reinterpret_cast<const ushort4*>(&xlr[(size_t)u * (2 * H) + fl * 4]);
      float x0 = bf2f(q.x), x1 = bf2f(q.y), x2 = bf2f(q.z), x3 = bf2f(q.w);
      float t = a4.x * lrelu02(x0 + xr0);
      t = fmaf(a4.y, lrelu02(x1 + xr1), t);
      t = fmaf(a4.z, lrelu02(x2 + xr2), t);
      t = fmaf(a4.w, lrelu02(x3 + xr3), t);
#pragma unroll
      for (int o = L / 2; o >= 1; o >>= 1) t += __shfl_xor(t, o);
      float diff = t - mA;
      if (diff > 8.f) {
        float sc = __expf(-diff);
        dA *= sc;
        accA.x *= sc; accA.y *= sc; accA.z *= sc; accA.w *= sc;
        mA = t; diff = 0.f;
      }
      float w = __expf(diff);
      dA += w;
      accA.x = fmaf(w, x0, accA.x);
      accA.y = fmaf(w, x1, accA.y);
      accA.z = fmaf(w, x2, accA.z);
      accA.w = fmaf(w, x3, accA.w);
    }
    if (UN2) {
      int j2 = j + C;
      if (j2 < end) {
        int u = ssrc[j2];
        ushort4 q = *reinterpret_cast<const ushort4*>(&xlr[(size_t)u * (2 * H) + fl * 4]);
        float x0 = bf2f(q.x), x1 = bf2f(q.y), x2 = bf2f(q.z), x3 = bf2f(q.w);
        float t = a4.x * lrelu02(x0 + xr0);
        t = fmaf(a4.y, lrelu02(x1 + xr1), t);
        t = fmaf(a4.z, lrelu02(x2 + xr2), t);
        t = fmaf(a4.w, lrelu02(x3 + xr3), t);
#pragma unroll
        for (int o = L / 2; o >= 1; o >>= 1) t += __shfl_xor(t, o);
        float diff = t - mB;
        if (diff > 8.f) {
          float sc = __expf(-diff);
          dB *= sc;
          accB.x *= sc; accB.y *= sc; accB.z *= sc; accB.w *= sc;
          mB = t; diff = 0.f;
        }
        float w = __expf(diff);
        dB += w;
        accB.x = fmaf(w, x0, accB.x);
        accB.y = fmaf(w, x1, accB.y);
        accB.z = fmaf(w, x2, accB.z);
        accB.w = fmaf(w, x3, accB.w);
      }
    }
  }

  if (UN2) {
    float mn = fmaxf(mA, mB);
    float s1 = __expf(mA - mn), s2 = __expf(mB - mn);
    dA = dA * s1 + dB * s2;
    accA.x = accA.x * s1 + accB.x * s2;
    accA.y = accA.y * s1 + accB.y * s2;
    accA.z = accA.z * s1 + accB.z * s2;
    accA.w = accA.w * s1 + accB.w * s2;
    mA = mn;
  }

#pragma unroll
  for (int o = L; o < 64; o <<= 1) {
    float mo = __shfl_xor(mA, o);
    float d2 = __shfl_xor(dA, o);
    float ax = __shfl_xor(accA.x, o);
    float ay = __shfl_xor(accA.y, o);
    float az = __shfl_xor(accA.z, o);
    float aw = __shfl_xor(accA.w, o);
    float mn = fmaxf(mA, mo);
    float s1 = __expf(mA - mn), s2 = __expf(mo - mn);
    dA = dA * s1 + d2 * s2;
    accA.x = accA.x * s1 + ax * s2;
    accA.y = accA.y * s1 + ay * s2;
    accA.z = accA.z * s1 + az * s2;
    accA.w = accA.w * s1 + aw * s2;
    mA = mn;
  }

  if (lane < L) {
    float inv = 1.f / (dA + 1e-16f);
    const float4 b4 = *reinterpret_cast<const float4*>(&bias[fl * 4]);
    float4 o4 = make_float4(fmaf(accA.x, inv, b4.x), fmaf(accA.y, inv, b4.y),
                            fmaf(accA.z, inv, b4.z), fmaf(accA.w, inv, b4.w));
    *reinterpret_cast<float4*>(&out[(size_t)v * H + fl * 4]) = o4;
  }
}

// ---------------- BatchNorm ----------------
template <int H>
__global__ __launch_bounds__(256) void bn_stats(
    const float* __restrict__ X, float* __restrict__ stats, int N) {
  __shared__ float ls[256], ls2[256];
  int tid = threadIdx.x;
  int h = tid % H;
  constexpr int RPB = 256 / H;
  int r0 = blockIdx.x * RPB + tid / H;
  float s = 0.f, s2 = 0.f;
  for (int n = r0; n < N; n += gridDim.x * RPB) {
    float val = X[(size_t)n * H + h];
    s += val; s2 += val * val;
  }
  ls[tid] = s; ls2[tid] = s2;
  __syncthreads();
  if (tid < H) {
    for (int g = 1; g < RPB; g++) { s += ls[tid + g * H]; s2 += ls2[tid + g * H]; }
    atomicAdd(&stats[h], s);
    atomicAdd(&stats[H + h], s2);
  }
}

__global__ void bn_finalize(
    const float* __restrict__ stats, const float* __restrict__ gamma,
    const float* __restrict__ beta, float* __restrict__ ss, int H, int N) {
  int h = threadIdx.x;
  if (h < H) {
    float mean = stats[h] / (float)N;
    float var = stats[H + h] / (float)N - mean * mean;
    float istd = rsqrtf(var + 1e-5f);
    float sc = gamma[h] * istd;
    ss[h] = sc;
    ss[H + h] = beta[h] - mean * sc;
  }
}

// BN + ReLU elementwise, node-major bf16 output (feeds next MFMA GEMM)
template <int H>
__global__ __launch_bounds__(256) void bn_apply_b16(
    const float* __restrict__ X, const float* __restrict__ ss,
    unsigned short* __restrict__ Y, int N) {
  int g = blockIdx.x * 256 + threadIdx.x;
  if (g >= N * (H / 4)) return;
  int i = g * 4;
  int h = i & (H - 1);
  float4 v = *reinterpret_cast<const float4*>(&X[i]);
  float t0 = fmaxf(fmaf(v.x, ss[h + 0], ss[H + h + 0]), 0.f);
  float t1 = fmaxf(fmaf(v.y, ss[h + 1], ss[H + h + 1]), 0.f);
  float t2 = fmaxf(fmaf(v.z, ss[h + 2], ss[H + h + 2]), 0.f);
  float t3 = fmaxf(fmaf(v.w, ss[h + 3], ss[H + h + 3]), 0.f);
  uint2 o;
  o.x = (unsigned)f2bf(t0) | ((unsigned)f2bf(t1) << 16);
  o.y = (unsigned)f2bf(t2) | ((unsigned)f2bf(t3) << 16);
  *reinterpret_cast<uint2*>(&Y[i]) = o;
}

// ---------------- fused BN+ReLU + mean-pool, then final linear ------------
__global__ __launch_bounds__(256) void pool_kernel(
    const float* __restrict__ X, const float* __restrict__ ss,
    const int* __restrict__ batch, float* __restrict__ pool,
    float* __restrict__ cnt, int N) {
  __shared__ float lp[G_ * 16];
  __shared__ float lc[G_];
  int tid = threadIdx.x;
  for (int j = tid; j < G_ * 16; j += 256) lp[j] = 0.f;
  if (tid < G_) lc[tid] = 0.f;
  __syncthreads();
  int tot = N * 16;
  for (int i = blockIdx.x * 256 + tid; i < tot; i += gridDim.x * 256) {
    int n = i >> 4, h = i & 15;
    int g = batch[n];
    float t = X[i] * ss[h] + ss[16 + h];
    t = (t > 0.f) ? t : 0.f;
    atomicAdd(&lp[g * 16 + h], t);
    if (h == 0) atomicAdd(&lc[g], 1.0f);
  }
  __syncthreads();
  for (int j = tid; j < G_ * 16; j += 256) atomicAdd(&pool[j], lp[j]);
  if (tid < G_) atomicAdd(&cnt[tid], lc[tid]);
}

__global__ void final_linear(
    const float* __restrict__ pool, const float* __restrict__ cnt,
    const float* __restrict__ linW, const float* __restrict__ linb,
    float* __restrict__ out) {
  int g = threadIdx.x;
  if (g < G_) {
    float c = fmaxf(cnt[g], 1.0f);
    float acc = 0.f;
    for (int h = 0; h < 16; h++) acc += (pool[g * 16 + h] / c) * linW[h];
    out[g] = acc + linb[0];
  }
}

// ---------------- launch ----------------
extern "C" void kernel_launch(void* const* d_in, const int* in_sizes, int n_in,
                              void* d_out, int out_size, void* d_ws, size_t ws_size,
                              hipStream_t stream) {
  const float* x = (const float*)d_in[0];
  const int* ei = (const int*)d_in[1];
  const int* batch = (const int*)d_in[2];
  const int N = in_sizes[0] / 128;
  const int E = in_sizes[1] / 2;
  const int Etot = E + N;

  char* wsb = (char*)d_ws;
  size_t off = 0;
  auto alloc = [&](size_t bytes) -> void* {
    void* p = wsb + off;
    off += (bytes + 255) & ~(size_t)255;
    return p;
  };
  unsigned short* R1b = (unsigned short*)alloc((size_t)128 * N * 2);  // xlr bf16
  float* R2 = (float*)alloc((size_t)64 * N * 4);                      // agg out fp32
  unsigned short* hb = (unsigned short*)alloc((size_t)64 * N * 2);    // BN out bf16
  int* row_ptr = (int*)alloc((size_t)(N + 1) * 4);
  int* cursor = (int*)alloc((size_t)N * 4);
  int* bsums = (int*)alloc(4096);
  int* ssrc = (int*)alloc((size_t)Etot * 4);
  unsigned short* Wt1 = (unsigned short*)alloc(16384 * 2);
  float* bc1 = (float*)alloc(128 * 4);
  unsigned short* Wt2 = (unsigned short*)alloc(4096 * 2);
  float* bc2 = (float*)alloc(64 * 4);
  unsigned short* Wt3 = (unsigned short*)alloc(1024 * 2);
  float* bc3 = (float*)alloc(32 * 4);
  float* ss = (float*)alloc(128 * 4);
  // single zeroed region: deg[N] | stats1[128] | stats2[128] | stats3[128] | pool | cnt
  size_t zelems = (size_t)N + 3 * 128 + G_ * 16 + G_;
  char* zb = (char*)alloc(zelems * 4);
  int* deg = (int*)zb;
  float* stats1 = (float*)(zb + (size_t)N * 4);
  float* stats2 = stats1 + 128;
  float* stats3 = stats2 + 128;
  float* pool = stats3 + 128;
  float* cnt = pool + G_ * 16;

  const float* Wl1 = (const float*)d_in[3];  const float* bl1 = (const float*)d_in[4];
  const float* Wr1 = (const float*)d_in[5];  const float* br1 = (const float*)d_in[6];
  const float* att1 = (const float*)d_in[7]; const float* bias1 = (const float*)d_in[8];
  const float* g1 = (const float*)d_in[9];   const float* b1 = (const float*)d_in[10];
  const float* Wl2 = (const float*)d_in[11]; const float* bl2 = (const float*)d_in[12];
  const float* Wr2 = (const float*)d_in[13]; const float* br2 = (const float*)d_in[14];
  const float* att2 = (const float*)d_in[15]; const float* bias2 = (const float*)d_in[16];
  const float* g2 = (const float*)d_in[17];  const float* b2 = (const float*)d_in[18];
  const float* Wl3 = (const float*)d_in[19]; const float* bl3 = (const float*)d_in[20];
  const float* Wr3 = (const float*)d_in[21]; const float* br3 = (const float*)d_in[22];
  const float* att3 = (const float*)d_in[23]; const float* bias3 = (const float*)d_in[24];
  const float* g3 = (const float*)d_in[25];  const float* b3 = (const float*)d_in[26];
  const float* linW = (const float*)d_in[27]; const float* linb = (const float*)d_in[28];
  float* out = (float*)d_out;

  int nb = (N + 1023) / 1024;
  int nnodeblk = (N + 3) / 4;
  int ngemm = (N + 63) / 64;

  // weights + zero scratch
  pack_all<<<64, 256, 0, stream>>>(Wl1, Wr1, bl1, br1, Wl2, Wr2, bl2, br2,
                                   Wl3, Wr3, bl3, br3, Wt1, bc1, Wt2, bc2, Wt3, bc3);
  hipMemsetAsync(zb, 0, zelems * 4, stream);

  // CSR build (XCD-partitioned hist + scatter)
  edge_hist<<<4096, 256, 0, stream>>>(ei, deg, E, Etot, N);
  scan1<<<nb, 256, 0, stream>>>(deg, row_ptr, bsums, N);
  scan2<<<1, 256, 0, stream>>>(bsums, nb);
  scan3<<<(N + 255) / 256, 256, 0, stream>>>(row_ptr, cursor, bsums, N, Etot);
  scatter_edges<<<4096, 256, 0, stream>>>(ei, cursor, ssrc, E, Etot, N);

  // ---- layer 1 ----
  gemm_mfma<128, 128, true><<<ngemm, 256, 0, stream>>>(x, Wt1, bc1, R1b, N);
  gat_agg2<64, true><<<nnodeblk, 256, 0, stream>>>(R1b, att1, bias1, row_ptr, ssrc, R2, N);
  bn_stats<64><<<512, 256, 0, stream>>>(R2, stats1, N);
  bn_finalize<<<1, 64, 0, stream>>>(stats1, g1, b1, ss, 64, N);
  bn_apply_b16<64><<<(N * 16 + 255) / 256, 256, 0, stream>>>(R2, ss, hb, N);

  // ---- layer 2 ----
  gemm_mfma<64, 64, false><<<ngemm, 256, 0, stream>>>(hb, Wt2, bc2, R1b, N);
  gat_agg2<32, true><<<nnodeblk, 256, 0, stream>>>(R1b, att2, bias2, row_ptr, ssrc, R2, N);
  bn_stats<32><<<512, 256, 0, stream>>>(R2, stats2, N);
  bn_finalize<<<1, 64, 0, stream>>>(stats2, g2, b2, ss, 32, N);
  bn_apply_b16<32><<<(N * 8 + 255) / 256, 256, 0, stream>>>(R2, ss, hb, N);

  // ---- layer 3 ----
  gemm_mfma<32, 32, false><<<ngemm, 256, 0, stream>>>(hb, Wt3, bc3, R1b, N);
  gat_agg2<16, false><<<nnodeblk, 256, 0, stream>>>(R1b, att3, bias3, row_ptr, ssrc, R2, N);
  bn_stats<16><<<512, 256, 0, stream>>>(R2, stats3, N);
  bn_finalize<<<1, 64, 0, stream>>>(stats3, g3, b3, ss, 16, N);

  // ---- fused BN+ReLU+pool + linear ----
  pool_kernel<<<2048, 256, 0, stream>>>(R2, ss, batch, pool, cnt, N);
  final_linear<<<1, 64, 0, stream>>>(pool, cnt, linW, linb, out);
}